// Round 4
// baseline (739.633 us; speedup 1.0000x reference)
//
#include <hip/hip_runtime.h>
#include <hip/hip_bf16.h>

// HierarchicalMambaBlock: B=2,T=1024,DIM=512 -> D_INNER=1024, DT_RANK=64, D_STATE=16
// All external tensors f32. GEMMs run on MFMA via bf16x3 K-concat split:
//   A' = [Ah | Al | Ah], W' = [Wh | Wh | Wl]  => A'.W'^T = AhWh + AlWh + AhWl  (~f32 accurate)
#define BATCH   2
#define SEQ     1024
#define DIMSZ   512
#define DINNER  1024
#define DTRANK  64
#define DSTATE  16
#define CHUNK   32

typedef __hip_bfloat16 bf16;
typedef __attribute__((ext_vector_type(8))) short s8v;   // 8 bf16 (4 VGPR) MFMA frag
typedef __attribute__((ext_vector_type(4))) float f4v;   // 4 f32 acc

__device__ __forceinline__ float sigmoidf_(float x) { return 1.f / (1.f + __expf(-x)); }
__device__ __forceinline__ float siluf_(float x) { return x * sigmoidf_(x); }
__device__ __forceinline__ float bf2f(bf16 v) { return __bfloat162float(v); }
__device__ __forceinline__ void split2(float v, bf16& hi, bf16& lo) {
    hi = __float2bfloat16(v);
    lo = __float2bfloat16(v - __bfloat162float(hi));
}

// ---------------------------------------------------------------------------
// MFMA GEMM: C[M,N] = act(A3[M,K3] @ W3[N,K3]^T (+bias)) (+res)
// A3/W3 bf16 (K-concat split operands). Tile 128x128, BK=64, 4 waves, each
// wave 4x4 of 16x16x32 MFMA. Grids exact (M,N multiples of 128; K3 of 64).
// ACT: 0 none, 1 silu, 2 sigmoid, 3 bias+softplus
// OUTMODE: 0 -> f32 C (ldc=N), 1 -> bf16x3 A-layout [hi|lo|hi] (row stride 3N)
// ---------------------------------------------------------------------------
template <int ACT, int OUTMODE, bool ADD_RES>
__global__ __launch_bounds__(256) void mgemm_kernel(
    const bf16* __restrict__ A3, int K3,
    const bf16* __restrict__ W3,
    const float* __restrict__ bias,
    const float* __restrict__ res,
    float* __restrict__ Cf,
    bf16* __restrict__ Cb3,
    int N)
{
    __shared__ bf16 As[128][64];
    __shared__ bf16 Bs[128][64];
    const int m0 = blockIdx.x * 128;
    const int n0 = blockIdx.y * 128;
    const int tid = threadIdx.x;
    const int wave = tid >> 6;
    const int lane = tid & 63;
    const int wm = (wave >> 1) * 64;
    const int wn = (wave & 1) * 64;
    const int m16 = lane & 15;
    const int q   = lane >> 4;

    f4v acc[4][4];
#pragma unroll
    for (int i = 0; i < 4; i++)
#pragma unroll
        for (int j = 0; j < 4; j++)
#pragma unroll
            for (int r = 0; r < 4; r++) acc[i][j][r] = 0.f;

    const int cch = tid & 7;        // 16B chunk index within 64-bf16 row
    const int c8  = cch * 8;
    const int r0  = tid >> 3;       // 0..31

    const int nkt = K3 >> 6;
    for (int kt = 0; kt < nkt; kt++) {
        const int kb = kt * 64;
        uint4 ra[4], rb[4];
#pragma unroll
        for (int p = 0; p < 4; p++) {
            int r = r0 + p * 32;
            ra[p] = *reinterpret_cast<const uint4*>(A3 + (size_t)(m0 + r) * K3 + kb + c8);
            rb[p] = *reinterpret_cast<const uint4*>(W3 + (size_t)(n0 + r) * K3 + kb + c8);
        }
        __syncthreads();   // previous iteration's LDS reads complete
#pragma unroll
        for (int p = 0; p < 4; p++) {
            int r = r0 + p * 32;
            int sc = (cch ^ (r & 7)) * 8;   // XOR swizzle on 16B chunks
            *reinterpret_cast<uint4*>(&As[r][sc]) = ra[p];
            *reinterpret_cast<uint4*>(&Bs[r][sc]) = rb[p];
        }
        __syncthreads();
#pragma unroll
        for (int kk = 0; kk < 2; kk++) {
            s8v af[4], bfr[4];
            const int clog = kk * 4 + q;
#pragma unroll
            for (int i = 0; i < 4; i++) {
                int ar = wm + i * 16 + m16;
                af[i]  = *reinterpret_cast<const s8v*>(&As[ar][(clog ^ (ar & 7)) * 8]);
                int br = wn + i * 16 + m16;
                bfr[i] = *reinterpret_cast<const s8v*>(&Bs[br][(clog ^ (br & 7)) * 8]);
            }
#pragma unroll
            for (int i = 0; i < 4; i++)
#pragma unroll
                for (int j = 0; j < 4; j++)
                    acc[i][j] = __builtin_amdgcn_mfma_f32_16x16x32_bf16(
                        af[i], bfr[j], acc[i][j], 0, 0, 0);
        }
    }

    // Epilogue. D mapping (verified): row = q*4 + reg, col = lane&15.
#pragma unroll
    for (int i = 0; i < 4; i++) {
#pragma unroll
        for (int j = 0; j < 4; j++) {
#pragma unroll
            for (int r = 0; r < 4; r++) {
                int gm = m0 + wm + i * 16 + q * 4 + r;
                int gn = n0 + wn + j * 16 + m16;
                float v = acc[i][j][r];
                if (ACT == 3) { v += bias[gn]; v = (v > 20.f) ? v : __logf(1.f + __expf(v)); }
                else if (ACT == 1) v = siluf_(v);
                else if (ACT == 2) v = sigmoidf_(v);
                if (ADD_RES) v += res[(size_t)gm * N + gn];
                if (OUTMODE == 0) {
                    Cf[(size_t)gm * N + gn] = v;
                } else {
                    bf16 hi, lo; split2(v, hi, lo);
                    size_t rb_ = (size_t)gm * 3 * N;
                    Cb3[rb_ + gn] = hi;
                    Cb3[rb_ + N + gn] = lo;
                    Cb3[rb_ + 2 * N + gn] = hi;
                }
            }
        }
    }
}

// ---------------------------------------------------------------------------
// Conversion kernels (f32 -> bf16x3 split layouts)
// ---------------------------------------------------------------------------
// Weights: [Wh|Wh|Wl]. Tensors packed by range; all K are powers of two.
__global__ void convert_weights_kernel(
    const float* __restrict__ w_in, const float* __restrict__ w_cg1,
    const float* __restrict__ w_cg2, const float* __restrict__ w_out,
    const float* __restrict__ w_dt,
    bf16* __restrict__ o_in, bf16* __restrict__ o_cg1, bf16* __restrict__ o_cg2,
    bf16* __restrict__ o_out, bf16* __restrict__ o_dt)
{
    int idx = blockIdx.x * blockDim.x + threadIdx.x;
    const float* src; bf16* dst; int lk; int rel;
    if (idx < 1048576)      { src = w_in;  dst = o_in;  lk = 9;  rel = idx; }
    else if (idx < 1572864) { src = w_cg1; dst = o_cg1; lk = 10; rel = idx - 1048576; }
    else if (idx < 2097152) { src = w_cg2; dst = o_cg2; lk = 9;  rel = idx - 1572864; }
    else if (idx < 2621440) { src = w_out; dst = o_out; lk = 10; rel = idx - 2097152; }
    else                    { src = w_dt;  dst = o_dt;  lk = 6;  rel = idx - 2621440; }
    int K = 1 << lk;
    int n = rel >> lk, k = rel & (K - 1);
    float v = src[rel];
    bf16 hi, lo; split2(v, hi, lo);
    size_t base = (size_t)n * 3 * K;
    dst[base + k] = hi;
    dst[base + K + k] = hi;
    dst[base + 2 * K + k] = lo;
}

// x -> A-layout [hi|lo|hi], K=512
__global__ void convert_x_kernel(const float* __restrict__ x, bf16* __restrict__ x3)
{
    int idx = blockIdx.x * blockDim.x + threadIdx.x;   // 2048*512
    int m = idx >> 9, k = idx & 511;
    bf16 hi, lo; split2(x[idx], hi, lo);
    size_t base = (size_t)m * 1536;
    x3[base + k] = hi;
    x3[base + 512 + k] = lo;
    x3[base + 1024 + k] = hi;
}

// dt_raw = pj[:, 0:64] (3 scales stacked: rows 0..2047, 2048..3071, 3072..3583)
__global__ void convert_dtraw_kernel(const float* __restrict__ pj0,
                                     const float* __restrict__ pj1,
                                     const float* __restrict__ pj2,
                                     bf16* __restrict__ dtA)
{
    int idx = blockIdx.x * blockDim.x + threadIdx.x;   // 3584*64
    int row = idx >> 6, k = idx & 63;
    float v;
    if (row < 2048)      v = pj0[(size_t)row * 96 + k];
    else if (row < 3072) v = pj1[(size_t)(row - 2048) * 96 + k];
    else                 v = pj2[(size_t)(row - 3072) * 96 + k];
    bf16 hi, lo; split2(v, hi, lo);
    size_t base = (size_t)row * 192;
    dtA[base + k] = hi;
    dtA[base + 64 + k] = lo;
    dtA[base + 128 + k] = hi;
}

// ---------------------------------------------------------------------------
// xproj (f32 VALU, N=96 is MFMA-hostile): all 3 scales in one launch.
// Blocks: s0 -> 0..63 (32 mb x 2 nb), s1 -> 64..95, s2 -> 96..111.
// ---------------------------------------------------------------------------
__global__ __launch_bounds__(256) void xproj_kernel(
    const float* __restrict__ xc0, const float* __restrict__ xc1,
    const float* __restrict__ xc2, const float* __restrict__ xw,
    float* __restrict__ pj0, float* __restrict__ pj1, float* __restrict__ pj2)
{
    int gx = blockIdx.x;
    int s, loc;
    if (gx < 64)      { s = 0; loc = gx; }
    else if (gx < 96) { s = 1; loc = gx - 64; }
    else              { s = 2; loc = gx - 96; }
    const float* A = (s == 0) ? xc0 : (s == 1) ? xc1 : xc2;
    float* C       = (s == 0) ? pj0 : (s == 1) ? pj1 : pj2;
    const float* W = xw + s * 96 * 1024;
    const int m0 = (loc >> 1) * 64;
    const int n0 = (loc & 1) * 64;

    const int BK = 16;
    __shared__ __align__(16) float As[BK][64 + 4];
    __shared__ __align__(16) float Bs[BK][64 + 4];
    const int tid = threadIdx.x;
    const int ty = tid >> 4, tx = tid & 15;
    const int arow = tid >> 2, acol = (tid & 3) * 4;

    float acc[4][4] = {};
    for (int k0 = 0; k0 < 1024; k0 += BK) {
        {
            float4 v = *reinterpret_cast<const float4*>(A + (size_t)(m0 + arow) * 1024 + k0 + acol);
            As[acol + 0][arow] = v.x; As[acol + 1][arow] = v.y;
            As[acol + 2][arow] = v.z; As[acol + 3][arow] = v.w;
        }
        {
            int n = n0 + arow;
            float4 v = make_float4(0.f, 0.f, 0.f, 0.f);
            if (n < 96)
                v = *reinterpret_cast<const float4*>(W + (size_t)n * 1024 + k0 + acol);
            Bs[acol + 0][arow] = v.x; Bs[acol + 1][arow] = v.y;
            Bs[acol + 2][arow] = v.z; Bs[acol + 3][arow] = v.w;
        }
        __syncthreads();
#pragma unroll
        for (int k = 0; k < BK; k++) {
            const float4 av = *reinterpret_cast<const float4*>(&As[k][ty * 4]);
            const float4 bv = *reinterpret_cast<const float4*>(&Bs[k][tx * 4]);
            float a[4] = { av.x, av.y, av.z, av.w };
            float b[4] = { bv.x, bv.y, bv.z, bv.w };
#pragma unroll
            for (int i = 0; i < 4; i++)
#pragma unroll
                for (int j = 0; j < 4; j++)
                    acc[i][j] = fmaf(a[i], b[j], acc[i][j]);
        }
        __syncthreads();
    }
#pragma unroll
    for (int i = 0; i < 4; i++)
#pragma unroll
        for (int j = 0; j < 4; j++) {
            int n = n0 + tx * 4 + j;
            if (n < 96)
                C[(size_t)(m0 + ty * 4 + i) * 96 + n] = acc[i][j];
        }
}

// ---------------------------------------------------------------------------
__global__ void downsample_kernel(const float* __restrict__ X, int ldx,
                                  int Tout, int stride, float* __restrict__ out)
{
    int idx = blockIdx.x * blockDim.x + threadIdx.x;
    if (idx >= BATCH * Tout * DINNER) return;
    int c = idx & (DINNER - 1);
    int row = idx >> 10;
    int b = row / Tout;
    int t = row - b * Tout;
    const float* base = X + ((size_t)(b * Tout * stride) + (size_t)t * stride) * ldx + c;
    float s = 0.f;
    for (int k = 0; k < stride; k++) s += base[(size_t)k * ldx];
    out[idx] = s * (1.f / (float)stride);
}

__global__ void conv_silu_kernel(const float* __restrict__ X, int ldx, int Ts,
                                 const float* __restrict__ cw,
                                 const float* __restrict__ cb,
                                 float* __restrict__ out)
{
    int idx = blockIdx.x * blockDim.x + threadIdx.x;
    if (idx >= BATCH * Ts * DINNER) return;
    int c = idx & (DINNER - 1);
    int row = idx >> 10;
    int b = row / Ts;
    int t = row - b * Ts;
    float acc = cb[c];
    const float* base = X + (size_t)(b * Ts) * ldx;
#pragma unroll
    for (int k = 0; k < 4; k++) {
        int tt = t - 3 + k;
        if (tt >= 0) acc = fmaf(cw[c * 4 + k], base[(size_t)tt * ldx + c], acc);
    }
    out[idx] = siluf_(acc);
}

// ---------------------------------------------------------------------------
// Chunked selective scan (unchanged from passing round 3)
// ---------------------------------------------------------------------------
__device__ __forceinline__ void scan_decode(int blk, int& s, int& nchunk, int& Ts,
                                            int& dquad, int& chunk, int& b, size_t& soff)
{
    int local;
    if (blk < 256)      { s = 0; local = blk;       soff = 0; }
    else if (blk < 384) { s = 1; local = blk - 256; soff = 1048576; }
    else                { s = 2; local = blk - 384; soff = 1572864; }
    nchunk = 32 >> s;
    Ts = 1024 >> s;
    dquad = local & 3;
    chunk = (local >> 2) & (nchunk - 1);
    b = local >> (7 - s);
}

__global__ __launch_bounds__(256) void scan_pass1(
    const float* __restrict__ dt0, const float* __restrict__ xc0, const float* __restrict__ pj0,
    const float* __restrict__ dt1, const float* __restrict__ xc1, const float* __restrict__ pj1,
    const float* __restrict__ dt2, const float* __restrict__ xc2, const float* __restrict__ pj2,
    const float* __restrict__ A_log,
    float* __restrict__ prodA_buf, float* __restrict__ h_buf)
{
    int s, nchunk, Ts, dquad, chunk, b; size_t soff;
    scan_decode(blockIdx.x, s, nchunk, Ts, dquad, chunk, b, soff);
    const float* dt = (s == 0) ? dt0 : (s == 1) ? dt1 : dt2;
    const float* xc = (s == 0) ? xc0 : (s == 1) ? xc1 : xc2;
    const float* pj = (s == 0) ? pj0 : (s == 1) ? pj1 : pj2;

    const int d = dquad * 256 + threadIdx.x;
    const size_t rowbase = (size_t)b * Ts;
    const int t0 = chunk * CHUNK;

    float Acoef[16], h[16], p[16];
#pragma unroll
    for (int j = 0; j < 16; j++) {
        Acoef[j] = -__expf(A_log[((size_t)(s * DINNER + d)) * 16 + j]);
        h[j] = 0.f; p[j] = 1.f;
    }

    __shared__ float bcB[CHUNK][16];
    for (int u = threadIdx.x; u < CHUNK * 16; u += 256) {
        int i = u >> 4, jj = u & 15;
        bcB[i][jj] = pj[(rowbase + t0 + i) * 96 + 64 + jj];
    }
    __syncthreads();

    for (int i = 0; i < CHUNK; i++) {
        size_t t = rowbase + t0 + i;
        float dtv = dt[t * DINNER + d];
        float xv  = xc[t * DINNER + d];
#pragma unroll
        for (int j = 0; j < 16; j++) {
            float dA  = fmaxf(__expf(dtv * Acoef[j]), 1e-38f);
            float dbx = fmaxf(dtv * bcB[i][j] * xv, 1e-38f);
            h[j] = fmaf(dA, h[j], dbx);
            p[j] *= dA;
        }
    }

    size_t base = soff + (size_t)((b * nchunk + chunk) * 16) * 1024 + d;
#pragma unroll
    for (int j = 0; j < 16; j++) {
        prodA_buf[base + (size_t)j * 1024] = p[j];
        h_buf[base + (size_t)j * 1024] = h[j];
    }
}

__global__ __launch_bounds__(256) void scan_pass2(
    const float* __restrict__ dt0, const float* __restrict__ xc0,
    const float* __restrict__ pj0, float* __restrict__ y0,
    const float* __restrict__ dt1, const float* __restrict__ xc1,
    const float* __restrict__ pj1, float* __restrict__ y1,
    const float* __restrict__ dt2, const float* __restrict__ xc2,
    const float* __restrict__ pj2, float* __restrict__ y2,
    const float* __restrict__ A_log, const float* __restrict__ D_p,
    const float* __restrict__ prodA_buf, const float* __restrict__ h_buf)
{
    int s, nchunk, Ts, dquad, chunk, b; size_t soff;
    scan_decode(blockIdx.x, s, nchunk, Ts, dquad, chunk, b, soff);
    const float* dt = (s == 0) ? dt0 : (s == 1) ? dt1 : dt2;
    const float* xc = (s == 0) ? xc0 : (s == 1) ? xc1 : xc2;
    const float* pj = (s == 0) ? pj0 : (s == 1) ? pj1 : pj2;
    float* y        = (s == 0) ? y0  : (s == 1) ? y1  : y2;

    const int d = dquad * 256 + threadIdx.x;
    const size_t rowbase = (size_t)b * Ts;
    const int t0 = chunk * CHUNK;

    float Acoef[16], h[16];
#pragma unroll
    for (int j = 0; j < 16; j++) {
        Acoef[j] = -__expf(A_log[((size_t)(s * DINNER + d)) * 16 + j]);
        h[j] = 0.f;
    }
    const float Dp = D_p[s * DINNER + d];

    for (int c = 0; c < chunk; c++) {
        size_t cb = soff + (size_t)((b * nchunk + c) * 16) * 1024 + d;
#pragma unroll
        for (int j = 0; j < 16; j++)
            h[j] = fmaf(prodA_buf[cb + (size_t)j * 1024], h[j], h_buf[cb + (size_t)j * 1024]);
    }

    __shared__ float bc[CHUNK][32];
    for (int u = threadIdx.x; u < CHUNK * 32; u += 256) {
        int i = u >> 5, jj = u & 31;
        bc[i][jj] = pj[(rowbase + t0 + i) * 96 + 64 + jj];
    }
    __syncthreads();

    for (int i = 0; i < CHUNK; i++) {
        size_t t = rowbase + t0 + i;
        float dtv = dt[t * DINNER + d];
        float xv  = xc[t * DINNER + d];
        float accy = 0.f;
#pragma unroll
        for (int j = 0; j < 16; j++) {
            float dA  = fmaxf(__expf(dtv * Acoef[j]), 1e-38f);
            float dbx = fmaxf(dtv * bc[i][j] * xv, 1e-38f);
            h[j] = fmaf(dA, h[j], dbx);
            accy = fmaf(bc[i][16 + j], h[j], accy);
        }
        y[t * DINNER + d] = accy + Dp * xv;
    }
}

// ---------------------------------------------------------------------------
// fused (f32) + ctx (bf16x3 A-layout, for cg1)
__global__ void fuse_kernel(const float* __restrict__ y0, const float* __restrict__ y1,
                            const float* __restrict__ y2, const float* __restrict__ sw,
                            float* __restrict__ fused, bf16* __restrict__ ctx3)
{
    int idx = blockIdx.x * blockDim.x + threadIdx.x;
    if (idx >= BATCH * SEQ * DINNER) return;
    int d = idx & (DINNER - 1);
    int t = (idx >> 10) & (SEQ - 1);
    int b = idx >> 20;
    float v0 = y0[idx];
    float v1 = y1[((size_t)(b * 512) + (t >> 1)) * DINNER + d];
    float v2 = y2[((size_t)(b * 256) + (t >> 2)) * DINNER + d];
    float s0 = sw[0], s1 = sw[1], s2 = sw[2];
    float mx = fmaxf(s0, fmaxf(s1, s2));
    float e0 = __expf(s0 - mx), e1 = __expf(s1 - mx), e2 = __expf(s2 - mx);
    float inv = 1.f / (e0 + e1 + e2);
    fused[idx] = (e0 * v0 + e1 * v1 + e2 * v2) * inv;
    float ctxv = (v0 + v1 + v2) * (1.f / 3.f);
    bf16 hi, lo; split2(ctxv, hi, lo);
    size_t rb = (size_t)(idx >> 10) * 3072;
    ctx3[rb + d] = hi;
    ctx3[rb + 1024 + d] = lo;
    ctx3[rb + 2048 + d] = hi;
}

// fused' (bf16x3) = fused * cg * silu(gate)
__global__ void gate_mul_kernel(const float* __restrict__ fused, const float* __restrict__ cg,
                                const float* __restrict__ xz, bf16* __restrict__ fused3)
{
    int idx = blockIdx.x * blockDim.x + threadIdx.x;
    if (idx >= BATCH * SEQ * DINNER) return;
    int token = idx >> 10;
    int d = idx & (DINNER - 1);
    float g = xz[(size_t)token * 2048 + 1024 + d];
    float v = fused[idx] * cg[idx] * siluf_(g);
    bf16 hi, lo; split2(v, hi, lo);
    size_t rb = (size_t)token * 3072;
    fused3[rb + d] = hi;
    fused3[rb + 1024 + d] = lo;
    fused3[rb + 2048 + d] = hi;
}

__global__ __launch_bounds__(256) void ln_kernel(
    const float* __restrict__ yin, const float* __restrict__ gamma,
    const float* __restrict__ beta, float* __restrict__ out)
{
    int token = blockIdx.x;
    int tid = threadIdx.x;
    const float* row = yin + (size_t)token * DIMSZ;
    float v0 = row[tid], v1 = row[tid + 256];
    __shared__ float s1[256], s2[256];
    s1[tid] = v0 + v1;
    s2[tid] = v0 * v0 + v1 * v1;
    __syncthreads();
    for (int off = 128; off > 0; off >>= 1) {
        if (tid < off) { s1[tid] += s1[tid + off]; s2[tid] += s2[tid + off]; }
        __syncthreads();
    }
    float mu = s1[0] * (1.f / 512.f);
    float var = s2[0] * (1.f / 512.f) - mu * mu;
    float rstd = rsqrtf(var + 1e-5f);
    float* orow = out + (size_t)token * DIMSZ;
    orow[tid]       = (v0 - mu) * rstd * gamma[tid]       + beta[tid];
    orow[tid + 256] = (v1 - mu) * rstd * gamma[tid + 256] + beta[tid + 256];
}

// ---------------------------------------------------------------------------
extern "C" void kernel_launch(void* const* d_in, const int* in_sizes, int n_in,
                              void* d_out, int out_size, void* d_ws, size_t ws_size,
                              hipStream_t stream)
{
    const float* x         = (const float*)d_in[0];
    const float* in_proj_w = (const float*)d_in[1];
    const float* conv_w    = (const float*)d_in[2];
    const float* conv_b    = (const float*)d_in[3];
    const float* xproj_w   = (const float*)d_in[4];
    const float* dtproj_w  = (const float*)d_in[5];
    const float* dtproj_b  = (const float*)d_in[6];
    const float* A_log     = (const float*)d_in[7];
    const float* D_p       = (const float*)d_in[8];
    const float* scale_w   = (const float*)d_in[9];
    const float* cg_w1     = (const float*)d_in[10];
    const float* cg_w2     = (const float*)d_in[11];
    const float* out_pw    = (const float*)d_in[12];
    const float* ln_gamma  = (const float*)d_in[13];
    const float* ln_beta   = (const float*)d_in[14];
    float* out = (float*)d_out;

    float* ws = (float*)d_ws;
    // f32 base layout (element offsets) — same as round 3
    float* xz    = ws;                       // 4,194,304
    float* xs1   = xz    + 4194304;          // 1,048,576
    float* xs2   = xs1   + 1048576;          //   524,288
    float* xc0   = xs2   + 524288;           // 2,097,152
    float* xc1   = xc0   + 2097152;          // 1,048,576
    float* xc2   = xc1   + 1048576;          //   524,288
    float* pj0   = xc2   + 524288;           //   196,608
    float* pj1   = pj0   + 196608;           //    98,304
    float* pj2   = pj1   + 98304;            //    49,152
    float* dt0   = pj2   + 49152;            // 2,097,152
    float* dt1   = dt0   + 2097152;          // 1,048,576
    float* dt2   = dt1   + 1048576;          //   524,288
    float* y0    = dt2   + 524288;           // 2,097,152
    float* y1    = y0    + 2097152;          // 1,048,576
    float* y2    = y1    + 1048576;          //   524,288
    float* prodA = y2    + 524288;           // 1,835,008
    float* hbuf  = prodA + 1835008;          // 1,835,008
    // fresh bf16x3 buffers (float-sized slots)
    float* w_cg1f = hbuf + 1835008;          //   786,432 f (512 x 3072 bf16)
    float* w_cg2f = w_cg1f + 786432;         //   786,432 f (1024 x 1536)
    float* w_outf = w_cg2f + 786432;         //   786,432 f (512 x 3072)
    float* w_dtf  = w_outf + 786432;         //   294,912 f (3072 x 192)
    float* dtAf   = w_dtf  + 294912;         //   344,064 f (3584 x 192)
    // total: 23,789,568 floats = 95.2 MB

    // Overlays (lifetime-checked):
    bf16* w_in3  = (bf16*)y0;     // P0..P1 (in_proj); y0 written at scan (P6)
    bf16* x3     = (bf16*)y1;     // spans y1+y2 (1,572,864 f); dead after in_proj
    bf16* w_cg13 = (bf16*)w_cg1f;
    bf16* w_cg23 = (bf16*)w_cg2f;
    bf16* w_out3 = (bf16*)w_outf;
    bf16* w_dt3  = (bf16*)w_dtf;
    bf16* dtA3   = (bf16*)dtAf;
    bf16* ctx3   = (bf16*)dt0;    // spans dt0+dt1 (3,145,728 f worth); dead after scan
    bf16* h1cg3  = (bf16*)prodA;  // 1,572,864 f worth; dead after scan
    bf16* fused3 = (bf16*)y0;     // spans y0+y1; y dead after fuse
    float* fusedf = xc0;          // dead after scan
    float* cgf    = dt0;          // written after ctx3 is dead (post-cg1)
    float* outpre = xc1;          // dead after scan

    const int M0 = BATCH * SEQ;   // 2048

    // P0) conversions
    convert_weights_kernel<<<11008, 256, 0, stream>>>(
        in_proj_w, cg_w1, cg_w2, out_pw, dtproj_w,
        w_in3, w_cg13, w_cg23, w_out3, w_dt3);
    convert_x_kernel<<<4096, 256, 0, stream>>>(x, x3);

    // P1) in_proj: xz = x @ in_proj_w^T  (M=2048,N=2048,K3=1536)
    mgemm_kernel<0, 0, false><<<dim3(16, 16), 256, 0, stream>>>(
        x3, 1536, w_in3, nullptr, nullptr, xz, nullptr, 2048);

    // P2) downsample + conv
    downsample_kernel<<<(BATCH * 512 * DINNER) / 256, 256, 0, stream>>>(xz, 2048, 512, 2, xs1);
    downsample_kernel<<<(BATCH * 256 * DINNER) / 256, 256, 0, stream>>>(xz, 2048, 256, 4, xs2);
    conv_silu_kernel<<<(BATCH * 1024 * DINNER) / 256, 256, 0, stream>>>(
        xz, 2048, 1024, conv_w + 0 * 4096, conv_b + 0 * DINNER, xc0);
    conv_silu_kernel<<<(BATCH * 512 * DINNER) / 256, 256, 0, stream>>>(
        xs1, 1024, 512, conv_w + 1 * 4096, conv_b + 1 * DINNER, xc1);
    conv_silu_kernel<<<(BATCH * 256 * DINNER) / 256, 256, 0, stream>>>(
        xs2, 1024, 256, conv_w + 2 * 4096, conv_b + 2 * DINNER, xc2);

    // P3) xproj (all scales, one launch)
    xproj_kernel<<<112, 256, 0, stream>>>(xc0, xc1, xc2, xproj_w, pj0, pj1, pj2);

    // P4) dt_raw -> bf16x3
    convert_dtraw_kernel<<<896, 256, 0, stream>>>(pj0, pj1, pj2, dtA3);

    // P5) dtproj per scale: dt = softplus(dt_raw @ w^T + b)  (N=1024, K3=192)
    mgemm_kernel<3, 0, false><<<dim3(16, 8), 256, 0, stream>>>(
        dtA3, 192, w_dt3, dtproj_b, nullptr, dt0, nullptr, 1024);
    mgemm_kernel<3, 0, false><<<dim3(8, 8), 256, 0, stream>>>(
        dtA3 + (size_t)2048 * 192, 192, w_dt3 + (size_t)1024 * 192,
        dtproj_b + 1024, nullptr, dt1, nullptr, 1024);
    mgemm_kernel<3, 0, false><<<dim3(4, 8), 256, 0, stream>>>(
        dtA3 + (size_t)3072 * 192, 192, w_dt3 + (size_t)2048 * 192,
        dtproj_b + 2048, nullptr, dt2, nullptr, 1024);

    // P6) chunked selective scan
    scan_pass1<<<448, 256, 0, stream>>>(dt0, xc0, pj0, dt1, xc1, pj1,
                                        dt2, xc2, pj2, A_log, prodA, hbuf);
    scan_pass2<<<448, 256, 0, stream>>>(dt0, xc0, pj0, y0, dt1, xc1, pj1, y1,
                                        dt2, xc2, pj2, y2, A_log, D_p, prodA, hbuf);

    // P7) fuse -> fused f32 (xc0) + ctx bf16x3 (dt0/dt1)
    fuse_kernel<<<(BATCH * SEQ * DINNER) / 256, 256, 0, stream>>>(
        y0, y1, y2, scale_w, fusedf, ctx3);

    // P8) cg1: h1 = silu(ctx @ cg_w1^T) -> bf16x3 (N=512, K3=3072)
    mgemm_kernel<1, 1, false><<<dim3(16, 4), 256, 0, stream>>>(
        ctx3, 3072, w_cg13, nullptr, nullptr, nullptr, h1cg3, 512);

    // P9) cg2: cg = sigmoid(h1 @ cg_w2^T) -> f32 (N=1024, K3=1536)
    mgemm_kernel<2, 0, false><<<dim3(16, 8), 256, 0, stream>>>(
        h1cg3, 1536, w_cg23, nullptr, nullptr, cgf, nullptr, 1024);

    // P10) gate: fused' = fused * cg * silu(gate) -> bf16x3 (y0/y1)
    gate_mul_kernel<<<(BATCH * SEQ * DINNER) / 256, 256, 0, stream>>>(
        fusedf, cgf, xz, fused3);

    // P11) out_proj + residual: outpre = fused' @ out_pw^T + x (N=512, K3=3072)
    mgemm_kernel<0, 0, true><<<dim3(16, 4), 256, 0, stream>>>(
        fused3, 3072, w_out3, nullptr, x, outpre, nullptr, 512);

    // P12) LayerNorm
    ln_kernel<<<M0, 256, 0, stream>>>(outpre, ln_gamma, ln_beta, out);
}

// Round 5
// 595.256 us; speedup vs baseline: 1.2425x; 1.2425x over previous
//
#include <hip/hip_runtime.h>
#include <hip/hip_bf16.h>

// HierarchicalMambaBlock: B=2,T=1024,DIM=512 -> D_INNER=1024, DT_RANK=64, D_STATE=16
// All external tensors f32. GEMMs run on MFMA via bf16x3 K-concat split:
//   A' = [Ah | Al | Ah], W' = [Wh | Wh | Wl]  => A'.W'^T = AhWh + AlWh + AhWl  (~f32 accurate)
#define BATCH   2
#define SEQ     1024
#define DIMSZ   512
#define DINNER  1024
#define DTRANK  64
#define DSTATE  16
#define CHUNK   32

typedef __hip_bfloat16 bf16;
typedef __attribute__((ext_vector_type(8))) short s8v;   // 8 bf16 (4 VGPR) MFMA frag
typedef __attribute__((ext_vector_type(4))) float f4v;   // 4 f32 acc

__device__ __forceinline__ float sigmoidf_(float x) { return 1.f / (1.f + __expf(-x)); }
__device__ __forceinline__ float siluf_(float x) { return x * sigmoidf_(x); }
__device__ __forceinline__ float bf2f(bf16 v) { return __bfloat162float(v); }
__device__ __forceinline__ void split2(float v, bf16& hi, bf16& lo) {
    hi = __float2bfloat16(v);
    lo = __float2bfloat16(v - __bfloat162float(hi));
}

// ---------------------------------------------------------------------------
// MFMA GEMM, 64x64 tile, BK=64, 4 waves (each 32x32 = 2x2 frags of 16x16x32),
// single-stage register prefetch (loads for kt+1 issue before MFMA of kt).
// C[M,N] = act(A3[M,K3] @ W3[N,K3]^T (+bias)) (+res)
// ACT: 0 none, 1 silu, 2 sigmoid, 3 bias+softplus
// OUTMODE: 0 -> f32 C (ldc=N), 1 -> bf16x3 A-layout [hi|lo|hi] (row stride 3N)
// DT_MODE: fused dtproj — per-m-block scale s = row/1024-ish selects W/bias.
//   (M stacked 3584 = 2048 + 1024 + 512; boundaries are multiples of 64)
// ---------------------------------------------------------------------------
template <int ACT, int OUTMODE, bool ADD_RES, bool DT_MODE>
__global__ __launch_bounds__(256) void mgemm_kernel(
    const bf16* __restrict__ A3, int K3,
    const bf16* __restrict__ W3,
    const float* __restrict__ bias,
    const float* __restrict__ res,
    float* __restrict__ Cf,
    bf16* __restrict__ Cb3,
    int N)
{
    __shared__ bf16 As[64][64];   // 8 KB
    __shared__ bf16 Bs[64][64];   // 8 KB
    const int m0 = blockIdx.x * 64;
    const int n0 = blockIdx.y * 64;
    const int tid = threadIdx.x;
    const int wave = tid >> 6;
    const int lane = tid & 63;
    const int wm = (wave >> 1) * 32;
    const int wn = (wave & 1) * 32;
    const int m16 = lane & 15;
    const int q   = lane >> 4;

    // dtproj fusion: pick scale by row block
    int scale = 0;
    if (DT_MODE) scale = (m0 < 2048) ? 0 : ((m0 < 3072) ? 1 : 2);
    const bf16* Wp = DT_MODE ? (W3 + (size_t)scale * 1024 * K3) : W3;
    const float* bias_p = (ACT == 3) ? (DT_MODE ? bias + scale * N : bias) : nullptr;

    f4v acc[2][2];
#pragma unroll
    for (int i = 0; i < 2; i++)
#pragma unroll
        for (int j = 0; j < 2; j++)
#pragma unroll
            for (int r = 0; r < 4; r++) acc[i][j][r] = 0.f;

    const int cch = tid & 7;        // 16B chunk within 64-bf16 row
    const int c8  = cch * 8;
    const int r0  = tid >> 3;       // 0..31

    const bf16* Abase = A3 + (size_t)(m0 + r0) * K3 + c8;
    const bf16* Bbase = Wp + (size_t)(n0 + r0) * K3 + c8;
    const size_t rstep = (size_t)32 * K3;

    const int nkt = K3 >> 6;
    uint4 ra[2], rb[2];
    // prologue: loads for kt=0
#pragma unroll
    for (int p = 0; p < 2; p++) {
        ra[p] = *reinterpret_cast<const uint4*>(Abase + p * rstep);
        rb[p] = *reinterpret_cast<const uint4*>(Bbase + p * rstep);
    }

    for (int kt = 0; kt < nkt; kt++) {
        if (kt) __syncthreads();              // protect prev iter's LDS reads
#pragma unroll
        for (int p = 0; p < 2; p++) {         // (compiler waits vmcnt here)
            int r = r0 + p * 32;
            int sc = (cch ^ (r & 7)) * 8;     // XOR swizzle on 16B chunks
            *reinterpret_cast<uint4*>(&As[r][sc]) = ra[p];
            *reinterpret_cast<uint4*>(&Bs[r][sc]) = rb[p];
        }
        __syncthreads();
        if (kt + 1 < nkt) {                   // prefetch kt+1 (no wait)
            size_t off = (size_t)(kt + 1) * 64;
#pragma unroll
            for (int p = 0; p < 2; p++) {
                ra[p] = *reinterpret_cast<const uint4*>(Abase + off + p * rstep);
                rb[p] = *reinterpret_cast<const uint4*>(Bbase + off + p * rstep);
            }
        }
#pragma unroll
        for (int kk = 0; kk < 2; kk++) {
            const int clog = kk * 4 + q;
            s8v af[2], bfr[2];
#pragma unroll
            for (int i = 0; i < 2; i++) {
                int ar = wm + i * 16 + m16;
                af[i]  = *reinterpret_cast<const s8v*>(&As[ar][(clog ^ (ar & 7)) * 8]);
                int br = wn + i * 16 + m16;
                bfr[i] = *reinterpret_cast<const s8v*>(&Bs[br][(clog ^ (br & 7)) * 8]);
            }
#pragma unroll
            for (int i = 0; i < 2; i++)
#pragma unroll
                for (int j = 0; j < 2; j++)
                    acc[i][j] = __builtin_amdgcn_mfma_f32_16x16x32_bf16(
                        af[i], bfr[j], acc[i][j], 0, 0, 0);
        }
    }

    // Epilogue. D mapping (verified): row = q*4 + reg, col = lane&15.
#pragma unroll
    for (int i = 0; i < 2; i++) {
#pragma unroll
        for (int j = 0; j < 2; j++) {
#pragma unroll
            for (int r = 0; r < 4; r++) {
                int gm = m0 + wm + i * 16 + q * 4 + r;
                int gn = n0 + wn + j * 16 + m16;
                float v = acc[i][j][r];
                if (ACT == 3) { v += bias_p[gn]; v = (v > 20.f) ? v : __logf(1.f + __expf(v)); }
                else if (ACT == 1) v = siluf_(v);
                else if (ACT == 2) v = sigmoidf_(v);
                if (ADD_RES) v += res[(size_t)gm * N + gn];
                if (OUTMODE == 0) {
                    Cf[(size_t)gm * N + gn] = v;
                } else {
                    bf16 hi, lo; split2(v, hi, lo);
                    size_t rb_ = (size_t)gm * 3 * N;
                    Cb3[rb_ + gn] = hi;
                    Cb3[rb_ + N + gn] = lo;
                    Cb3[rb_ + 2 * N + gn] = hi;
                }
            }
        }
    }
}

// ---------------------------------------------------------------------------
// Conversion kernels (f32 -> bf16x3 split layouts)
// ---------------------------------------------------------------------------
__global__ void convert_weights_kernel(
    const float* __restrict__ w_in, const float* __restrict__ w_cg1,
    const float* __restrict__ w_cg2, const float* __restrict__ w_out,
    const float* __restrict__ w_dt,
    bf16* __restrict__ o_in, bf16* __restrict__ o_cg1, bf16* __restrict__ o_cg2,
    bf16* __restrict__ o_out, bf16* __restrict__ o_dt)
{
    int idx = blockIdx.x * blockDim.x + threadIdx.x;
    const float* src; bf16* dst; int lk; int rel;
    if (idx < 1048576)      { src = w_in;  dst = o_in;  lk = 9;  rel = idx; }
    else if (idx < 1572864) { src = w_cg1; dst = o_cg1; lk = 10; rel = idx - 1048576; }
    else if (idx < 2097152) { src = w_cg2; dst = o_cg2; lk = 9;  rel = idx - 1572864; }
    else if (idx < 2621440) { src = w_out; dst = o_out; lk = 10; rel = idx - 2097152; }
    else                    { src = w_dt;  dst = o_dt;  lk = 6;  rel = idx - 2621440; }
    int K = 1 << lk;
    int n = rel >> lk, k = rel & (K - 1);
    float v = src[rel];
    bf16 hi, lo; split2(v, hi, lo);
    size_t base = (size_t)n * 3 * K;
    dst[base + k] = hi;
    dst[base + K + k] = hi;
    dst[base + 2 * K + k] = lo;
}

__global__ void convert_x_kernel(const float* __restrict__ x, bf16* __restrict__ x3)
{
    int idx = blockIdx.x * blockDim.x + threadIdx.x;   // 2048*512
    int m = idx >> 9, k = idx & 511;
    bf16 hi, lo; split2(x[idx], hi, lo);
    size_t base = (size_t)m * 1536;
    x3[base + k] = hi;
    x3[base + 512 + k] = lo;
    x3[base + 1024 + k] = hi;
}

__global__ void convert_dtraw_kernel(const float* __restrict__ pj0,
                                     const float* __restrict__ pj1,
                                     const float* __restrict__ pj2,
                                     bf16* __restrict__ dtA)
{
    int idx = blockIdx.x * blockDim.x + threadIdx.x;   // 3584*64
    int row = idx >> 6, k = idx & 63;
    float v;
    if (row < 2048)      v = pj0[(size_t)row * 96 + k];
    else if (row < 3072) v = pj1[(size_t)(row - 2048) * 96 + k];
    else                 v = pj2[(size_t)(row - 3072) * 96 + k];
    bf16 hi, lo; split2(v, hi, lo);
    size_t base = (size_t)row * 192;
    dtA[base + k] = hi;
    dtA[base + 64 + k] = lo;
    dtA[base + 128 + k] = hi;
}

// ---------------------------------------------------------------------------
// xproj (f32 VALU, N=96): all 3 scales in one launch.
// ---------------------------------------------------------------------------
__global__ __launch_bounds__(256) void xproj_kernel(
    const float* __restrict__ xc0, const float* __restrict__ xc1,
    const float* __restrict__ xc2, const float* __restrict__ xw,
    float* __restrict__ pj0, float* __restrict__ pj1, float* __restrict__ pj2)
{
    int gx = blockIdx.x;
    int s, loc;
    if (gx < 64)      { s = 0; loc = gx; }
    else if (gx < 96) { s = 1; loc = gx - 64; }
    else              { s = 2; loc = gx - 96; }
    const float* A = (s == 0) ? xc0 : (s == 1) ? xc1 : xc2;
    float* C       = (s == 0) ? pj0 : (s == 1) ? pj1 : pj2;
    const float* W = xw + s * 96 * 1024;
    const int m0 = (loc >> 1) * 64;
    const int n0 = (loc & 1) * 64;

    const int BK = 16;
    __shared__ __align__(16) float As[BK][64 + 4];
    __shared__ __align__(16) float Bs[BK][64 + 4];
    const int tid = threadIdx.x;
    const int ty = tid >> 4, tx = tid & 15;
    const int arow = tid >> 2, acol = (tid & 3) * 4;

    float acc[4][4] = {};
    for (int k0 = 0; k0 < 1024; k0 += BK) {
        {
            float4 v = *reinterpret_cast<const float4*>(A + (size_t)(m0 + arow) * 1024 + k0 + acol);
            As[acol + 0][arow] = v.x; As[acol + 1][arow] = v.y;
            As[acol + 2][arow] = v.z; As[acol + 3][arow] = v.w;
        }
        {
            int n = n0 + arow;
            float4 v = make_float4(0.f, 0.f, 0.f, 0.f);
            if (n < 96)
                v = *reinterpret_cast<const float4*>(W + (size_t)n * 1024 + k0 + acol);
            Bs[acol + 0][arow] = v.x; Bs[acol + 1][arow] = v.y;
            Bs[acol + 2][arow] = v.z; Bs[acol + 3][arow] = v.w;
        }
        __syncthreads();
#pragma unroll
        for (int k = 0; k < BK; k++) {
            const float4 av = *reinterpret_cast<const float4*>(&As[k][ty * 4]);
            const float4 bv = *reinterpret_cast<const float4*>(&Bs[k][tx * 4]);
            float a[4] = { av.x, av.y, av.z, av.w };
            float b[4] = { bv.x, bv.y, bv.z, bv.w };
#pragma unroll
            for (int i = 0; i < 4; i++)
#pragma unroll
                for (int j = 0; j < 4; j++)
                    acc[i][j] = fmaf(a[i], b[j], acc[i][j]);
        }
        __syncthreads();
    }
#pragma unroll
    for (int i = 0; i < 4; i++)
#pragma unroll
        for (int j = 0; j < 4; j++) {
            int n = n0 + tx * 4 + j;
            if (n < 96)
                C[(size_t)(m0 + ty * 4 + i) * 96 + n] = acc[i][j];
        }
}

// ---------------------------------------------------------------------------
__global__ void downsample_kernel(const float* __restrict__ X, int ldx,
                                  int Tout, int stride, float* __restrict__ out)
{
    int idx = blockIdx.x * blockDim.x + threadIdx.x;
    if (idx >= BATCH * Tout * DINNER) return;
    int c = idx & (DINNER - 1);
    int row = idx >> 10;
    int b = row / Tout;
    int t = row - b * Tout;
    const float* base = X + ((size_t)(b * Tout * stride) + (size_t)t * stride) * ldx + c;
    float s = 0.f;
    for (int k = 0; k < stride; k++) s += base[(size_t)k * ldx];
    out[idx] = s * (1.f / (float)stride);
}

__global__ void conv_silu_kernel(const float* __restrict__ X, int ldx, int Ts,
                                 const float* __restrict__ cw,
                                 const float* __restrict__ cb,
                                 float* __restrict__ out)
{
    int idx = blockIdx.x * blockDim.x + threadIdx.x;
    if (idx >= BATCH * Ts * DINNER) return;
    int c = idx & (DINNER - 1);
    int row = idx >> 10;
    int b = row / Ts;
    int t = row - b * Ts;
    float acc = cb[c];
    const float* base = X + (size_t)(b * Ts) * ldx;
#pragma unroll
    for (int k = 0; k < 4; k++) {
        int tt = t - 3 + k;
        if (tt >= 0) acc = fmaf(cw[c * 4 + k], base[(size_t)tt * ldx + c], acc);
    }
    out[idx] = siluf_(acc);
}

// ---------------------------------------------------------------------------
// Chunked selective scan (unchanged, passing since round 3)
// ---------------------------------------------------------------------------
__device__ __forceinline__ void scan_decode(int blk, int& s, int& nchunk, int& Ts,
                                            int& dquad, int& chunk, int& b, size_t& soff)
{
    int local;
    if (blk < 256)      { s = 0; local = blk;       soff = 0; }
    else if (blk < 384) { s = 1; local = blk - 256; soff = 1048576; }
    else                { s = 2; local = blk - 384; soff = 1572864; }
    nchunk = 32 >> s;
    Ts = 1024 >> s;
    dquad = local & 3;
    chunk = (local >> 2) & (nchunk - 1);
    b = local >> (7 - s);
}

__global__ __launch_bounds__(256) void scan_pass1(
    const float* __restrict__ dt0, const float* __restrict__ xc0, const float* __restrict__ pj0,
    const float* __restrict__ dt1, const float* __restrict__ xc1, const float* __restrict__ pj1,
    const float* __restrict__ dt2, const float* __restrict__ xc2, const float* __restrict__ pj2,
    const float* __restrict__ A_log,
    float* __restrict__ prodA_buf, float* __restrict__ h_buf)
{
    int s, nchunk, Ts, dquad, chunk, b; size_t soff;
    scan_decode(blockIdx.x, s, nchunk, Ts, dquad, chunk, b, soff);
    const float* dt = (s == 0) ? dt0 : (s == 1) ? dt1 : dt2;
    const float* xc = (s == 0) ? xc0 : (s == 1) ? xc1 : xc2;
    const float* pj = (s == 0) ? pj0 : (s == 1) ? pj1 : pj2;

    const int d = dquad * 256 + threadIdx.x;
    const size_t rowbase = (size_t)b * Ts;
    const int t0 = chunk * CHUNK;

    float Acoef[16], h[16], p[16];
#pragma unroll
    for (int j = 0; j < 16; j++) {
        Acoef[j] = -__expf(A_log[((size_t)(s * DINNER + d)) * 16 + j]);
        h[j] = 0.f; p[j] = 1.f;
    }

    __shared__ float bcB[CHUNK][16];
    for (int u = threadIdx.x; u < CHUNK * 16; u += 256) {
        int i = u >> 4, jj = u & 15;
        bcB[i][jj] = pj[(rowbase + t0 + i) * 96 + 64 + jj];
    }
    __syncthreads();

    for (int i = 0; i < CHUNK; i++) {
        size_t t = rowbase + t0 + i;
        float dtv = dt[t * DINNER + d];
        float xv  = xc[t * DINNER + d];
#pragma unroll
        for (int j = 0; j < 16; j++) {
            float dA  = fmaxf(__expf(dtv * Acoef[j]), 1e-38f);
            float dbx = fmaxf(dtv * bcB[i][j] * xv, 1e-38f);
            h[j] = fmaf(dA, h[j], dbx);
            p[j] *= dA;
        }
    }

    size_t base = soff + (size_t)((b * nchunk + chunk) * 16) * 1024 + d;
#pragma unroll
    for (int j = 0; j < 16; j++) {
        prodA_buf[base + (size_t)j * 1024] = p[j];
        h_buf[base + (size_t)j * 1024] = h[j];
    }
}

__global__ __launch_bounds__(256) void scan_pass2(
    const float* __restrict__ dt0, const float* __restrict__ xc0,
    const float* __restrict__ pj0, float* __restrict__ y0,
    const float* __restrict__ dt1, const float* __restrict__ xc1,
    const float* __restrict__ pj1, float* __restrict__ y1,
    const float* __restrict__ dt2, const float* __restrict__ xc2,
    const float* __restrict__ pj2, float* __restrict__ y2,
    const float* __restrict__ A_log, const float* __restrict__ D_p,
    const float* __restrict__ prodA_buf, const float* __restrict__ h_buf)
{
    int s, nchunk, Ts, dquad, chunk, b; size_t soff;
    scan_decode(blockIdx.x, s, nchunk, Ts, dquad, chunk, b, soff);
    const float* dt = (s == 0) ? dt0 : (s == 1) ? dt1 : dt2;
    const float* xc = (s == 0) ? xc0 : (s == 1) ? xc1 : xc2;
    const float* pj = (s == 0) ? pj0 : (s == 1) ? pj1 : pj2;
    float* y        = (s == 0) ? y0  : (s == 1) ? y1  : y2;

    const int d = dquad * 256 + threadIdx.x;
    const size_t rowbase = (size_t)b * Ts;
    const int t0 = chunk * CHUNK;

    float Acoef[16], h[16];
#pragma unroll
    for (int j = 0; j < 16; j++) {
        Acoef[j] = -__expf(A_log[((size_t)(s * DINNER + d)) * 16 + j]);
        h[j] = 0.f;
    }
    const float Dp = D_p[s * DINNER + d];

    for (int c = 0; c < chunk; c++) {
        size_t cb = soff + (size_t)((b * nchunk + c) * 16) * 1024 + d;
#pragma unroll
        for (int j = 0; j < 16; j++)
            h[j] = fmaf(prodA_buf[cb + (size_t)j * 1024], h[j], h_buf[cb + (size_t)j * 1024]);
    }

    __shared__ float bc[CHUNK][32];
    for (int u = threadIdx.x; u < CHUNK * 32; u += 256) {
        int i = u >> 5, jj = u & 31;
        bc[i][jj] = pj[(rowbase + t0 + i) * 96 + 64 + jj];
    }
    __syncthreads();

    for (int i = 0; i < CHUNK; i++) {
        size_t t = rowbase + t0 + i;
        float dtv = dt[t * DINNER + d];
        float xv  = xc[t * DINNER + d];
        float accy = 0.f;
#pragma unroll
        for (int j = 0; j < 16; j++) {
            float dA  = fmaxf(__expf(dtv * Acoef[j]), 1e-38f);
            float dbx = fmaxf(dtv * bc[i][j] * xv, 1e-38f);
            h[j] = fmaf(dA, h[j], dbx);
            accy = fmaf(bc[i][16 + j], h[j], accy);
        }
        y[t * DINNER + d] = accy + Dp * xv;
    }
}

// ---------------------------------------------------------------------------
__global__ void fuse_kernel(const float* __restrict__ y0, const float* __restrict__ y1,
                            const float* __restrict__ y2, const float* __restrict__ sw,
                            float* __restrict__ fused, bf16* __restrict__ ctx3)
{
    int idx = blockIdx.x * blockDim.x + threadIdx.x;
    if (idx >= BATCH * SEQ * DINNER) return;
    int d = idx & (DINNER - 1);
    int t = (idx >> 10) & (SEQ - 1);
    int b = idx >> 20;
    float v0 = y0[idx];
    float v1 = y1[((size_t)(b * 512) + (t >> 1)) * DINNER + d];
    float v2 = y2[((size_t)(b * 256) + (t >> 2)) * DINNER + d];
    float s0 = sw[0], s1 = sw[1], s2 = sw[2];
    float mx = fmaxf(s0, fmaxf(s1, s2));
    float e0 = __expf(s0 - mx), e1 = __expf(s1 - mx), e2 = __expf(s2 - mx);
    float inv = 1.f / (e0 + e1 + e2);
    fused[idx] = (e0 * v0 + e1 * v1 + e2 * v2) * inv;
    float ctxv = (v0 + v1 + v2) * (1.f / 3.f);
    bf16 hi, lo; split2(ctxv, hi, lo);
    size_t rb = (size_t)(idx >> 10) * 3072;
    ctx3[rb + d] = hi;
    ctx3[rb + 1024 + d] = lo;
    ctx3[rb + 2048 + d] = hi;
}

__global__ void gate_mul_kernel(const float* __restrict__ fused, const float* __restrict__ cg,
                                const float* __restrict__ xz, bf16* __restrict__ fused3)
{
    int idx = blockIdx.x * blockDim.x + threadIdx.x;
    if (idx >= BATCH * SEQ * DINNER) return;
    int token = idx >> 10;
    int d = idx & (DINNER - 1);
    float g = xz[(size_t)token * 2048 + 1024 + d];
    float v = fused[idx] * cg[idx] * siluf_(g);
    bf16 hi, lo; split2(v, hi, lo);
    size_t rb = (size_t)token * 3072;
    fused3[rb + d] = hi;
    fused3[rb + 1024 + d] = lo;
    fused3[rb + 2048 + d] = hi;
}

__global__ __launch_bounds__(256) void ln_kernel(
    const float* __restrict__ yin, const float* __restrict__ gamma,
    const float* __restrict__ beta, float* __restrict__ out)
{
    int token = blockIdx.x;
    int tid = threadIdx.x;
    const float* row = yin + (size_t)token * DIMSZ;
    float v0 = row[tid], v1 = row[tid + 256];
    __shared__ float s1[256], s2[256];
    s1[tid] = v0 + v1;
    s2[tid] = v0 * v0 + v1 * v1;
    __syncthreads();
    for (int off = 128; off > 0; off >>= 1) {
        if (tid < off) { s1[tid] += s1[tid + off]; s2[tid] += s2[tid + off]; }
        __syncthreads();
    }
    float mu = s1[0] * (1.f / 512.f);
    float var = s2[0] * (1.f / 512.f) - mu * mu;
    float rstd = rsqrtf(var + 1e-5f);
    float* orow = out + (size_t)token * DIMSZ;
    orow[tid]       = (v0 - mu) * rstd * gamma[tid]       + beta[tid];
    orow[tid + 256] = (v1 - mu) * rstd * gamma[tid + 256] + beta[tid + 256];
}

// ---------------------------------------------------------------------------
extern "C" void kernel_launch(void* const* d_in, const int* in_sizes, int n_in,
                              void* d_out, int out_size, void* d_ws, size_t ws_size,
                              hipStream_t stream)
{
    const float* x         = (const float*)d_in[0];
    const float* in_proj_w = (const float*)d_in[1];
    const float* conv_w    = (const float*)d_in[2];
    const float* conv_b    = (const float*)d_in[3];
    const float* xproj_w   = (const float*)d_in[4];
    const float* dtproj_w  = (const float*)d_in[5];
    const float* dtproj_b  = (const float*)d_in[6];
    const float* A_log     = (const float*)d_in[7];
    const float* D_p       = (const float*)d_in[8];
    const float* scale_w   = (const float*)d_in[9];
    const float* cg_w1     = (const float*)d_in[10];
    const float* cg_w2     = (const float*)d_in[11];
    const float* out_pw    = (const float*)d_in[12];
    const float* ln_gamma  = (const float*)d_in[13];
    const float* ln_beta   = (const float*)d_in[14];
    float* out = (float*)d_out;

    float* ws = (float*)d_ws;
    // f32 base layout (element offsets)
    float* xz    = ws;                       // 4,194,304
    float* xs1   = xz    + 4194304;          // 1,048,576
    float* xs2   = xs1   + 1048576;          //   524,288
    float* xc0   = xs2   + 524288;           // 2,097,152
    float* xc1   = xc0   + 2097152;          // 1,048,576
    float* xc2   = xc1   + 1048576;          //   524,288
    float* pj0   = xc2   + 524288;           //   196,608
    float* pj1   = pj0   + 196608;           //    98,304
    float* pj2   = pj1   + 98304;            //    49,152
    float* dt0   = pj2   + 49152;            // 2,097,152  (dt0..dt2 contiguous: stacked M=3584)
    float* dt1   = dt0   + 2097152;          // 1,048,576
    float* dt2   = dt1   + 1048576;          //   524,288
    float* y0    = dt2   + 524288;           // 2,097,152
    float* y1    = y0    + 2097152;          // 1,048,576
    float* y2    = y1    + 1048576;          //   524,288
    float* prodA = y2    + 524288;           // 1,835,008
    float* hbuf  = prodA + 1835008;          // 1,835,008
    float* w_cg1f = hbuf + 1835008;          //   786,432 f (512 x 3072 bf16)
    float* w_cg2f = w_cg1f + 786432;         //   786,432 f (1024 x 1536)
    float* w_outf = w_cg2f + 786432;         //   786,432 f (512 x 3072)
    float* w_dtf  = w_outf + 786432;         //   294,912 f (3072 x 192)
    float* dtAf   = w_dtf  + 294912;         //   344,064 f (3584 x 192)
    // total: 23,789,568 floats = 95.2 MB

    // Overlays (lifetime-checked):
    bf16* w_in3  = (bf16*)y0;     // used P0..P1; y0 written at scan (P6)
    bf16* x3     = (bf16*)y1;     // spans y1+y2; dead after in_proj
    bf16* w_cg13 = (bf16*)w_cg1f;
    bf16* w_cg23 = (bf16*)w_cg2f;
    bf16* w_out3 = (bf16*)w_outf;
    bf16* w_dt3  = (bf16*)w_dtf;
    bf16* dtA3   = (bf16*)dtAf;
    bf16* ctx3   = (bf16*)dt0;    // spans dt0+dt1; dead after scan
    bf16* h1cg3  = (bf16*)prodA;  // dead after scan
    bf16* fused3 = (bf16*)y0;     // spans y0+y1; y dead after fuse
    float* fusedf = xc0;          // dead after scan
    float* cgf    = dt0;          // written after ctx3 is dead (post-cg1)
    float* outpre = xc1;          // dead after scan

    const int M0 = BATCH * SEQ;   // 2048

    // P0) conversions
    convert_weights_kernel<<<11008, 256, 0, stream>>>(
        in_proj_w, cg_w1, cg_w2, out_pw, dtproj_w,
        w_in3, w_cg13, w_cg23, w_out3, w_dt3);
    convert_x_kernel<<<4096, 256, 0, stream>>>(x, x3);

    // P1) in_proj: xz = x @ in_proj_w^T  (M=2048,N=2048,K3=1536) — 1024 blocks
    mgemm_kernel<0, 0, false, false><<<dim3(32, 32), 256, 0, stream>>>(
        x3, 1536, w_in3, nullptr, nullptr, xz, nullptr, 2048);

    // P2) downsample + conv
    downsample_kernel<<<(BATCH * 512 * DINNER) / 256, 256, 0, stream>>>(xz, 2048, 512, 2, xs1);
    downsample_kernel<<<(BATCH * 256 * DINNER) / 256, 256, 0, stream>>>(xz, 2048, 256, 4, xs2);
    conv_silu_kernel<<<(BATCH * 1024 * DINNER) / 256, 256, 0, stream>>>(
        xz, 2048, 1024, conv_w + 0 * 4096, conv_b + 0 * DINNER, xc0);
    conv_silu_kernel<<<(BATCH * 512 * DINNER) / 256, 256, 0, stream>>>(
        xs1, 1024, 512, conv_w + 1 * 4096, conv_b + 1 * DINNER, xc1);
    conv_silu_kernel<<<(BATCH * 256 * DINNER) / 256, 256, 0, stream>>>(
        xs2, 1024, 256, conv_w + 2 * 4096, conv_b + 2 * DINNER, xc2);

    // P3) xproj (all scales, one launch)
    xproj_kernel<<<112, 256, 0, stream>>>(xc0, xc1, xc2, xproj_w, pj0, pj1, pj2);

    // P4) dt_raw -> bf16x3
    convert_dtraw_kernel<<<896, 256, 0, stream>>>(pj0, pj1, pj2, dtA3);

    // P5) dtproj, all scales fused (stacked M=3584, N=1024, K3=192) — 896 blocks
    mgemm_kernel<3, 0, false, true><<<dim3(56, 16), 256, 0, stream>>>(
        dtA3, 192, w_dt3, dtproj_b, nullptr, dt0, nullptr, 1024);

    // P6) chunked selective scan
    scan_pass1<<<448, 256, 0, stream>>>(dt0, xc0, pj0, dt1, xc1, pj1,
                                        dt2, xc2, pj2, A_log, prodA, hbuf);
    scan_pass2<<<448, 256, 0, stream>>>(dt0, xc0, pj0, y0, dt1, xc1, pj1, y1,
                                        dt2, xc2, pj2, y2, A_log, D_p, prodA, hbuf);

    // P7) fuse -> fused f32 (xc0) + ctx bf16x3 (dt0/dt1)
    fuse_kernel<<<(BATCH * SEQ * DINNER) / 256, 256, 0, stream>>>(
        y0, y1, y2, scale_w, fusedf, ctx3);

    // P8) cg1: h1 = silu(ctx @ cg_w1^T) -> bf16x3 (N=512, K3=3072) — 256 blocks
    mgemm_kernel<1, 1, false, false><<<dim3(32, 8), 256, 0, stream>>>(
        ctx3, 3072, w_cg13, nullptr, nullptr, nullptr, h1cg3, 512);

    // P9) cg2: cg = sigmoid(h1 @ cg_w2^T) -> f32 (N=1024, K3=1536) — 512 blocks
    mgemm_kernel<2, 0, false, false><<<dim3(32, 16), 256, 0, stream>>>(
        h1cg3, 1536, w_cg23, nullptr, nullptr, cgf, nullptr, 1024);

    // P10) gate: fused' = fused * cg * silu(gate) -> bf16x3 (y0/y1)
    gate_mul_kernel<<<(BATCH * SEQ * DINNER) / 256, 256, 0, stream>>>(
        fusedf, cgf, xz, fused3);

    // P11) out_proj + residual (N=512, K3=3072) — 256 blocks
    mgemm_kernel<0, 0, true, false><<<dim3(32, 8), 256, 0, stream>>>(
        fused3, 3072, w_out3, nullptr, x, outpre, nullptr, 512);

    // P12) LayerNorm
    ln_kernel<<<M0, 256, 0, stream>>>(outpre, ln_gamma, ln_beta, out);
}

// Round 6
// 534.731 us; speedup vs baseline: 1.3832x; 1.1132x over previous
//
#include <hip/hip_runtime.h>
#include <hip/hip_bf16.h>

// HierarchicalMambaBlock: B=2,T=1024,DIM=512 -> D_INNER=1024, DT_RANK=64, D_STATE=16
// All external tensors f32. GEMMs on MFMA via bf16x3 K-concat split:
//   A' = [Ah | Al | Ah], W' = [Wh | Wh | Wl]  => A'.W'^T ≈ f32 GEMM
#define BATCH   2
#define SEQ     1024
#define DIMSZ   512
#define DINNER  1024
#define DTRANK  64
#define DSTATE  16
#define CHUNK   32

typedef __hip_bfloat16 bf16;
typedef __attribute__((ext_vector_type(8))) short s8v;   // 8 bf16 MFMA frag
typedef __attribute__((ext_vector_type(4))) float f4v;   // 4 f32 acc

__device__ __forceinline__ float sigmoidf_(float x) { return 1.f / (1.f + __expf(-x)); }
__device__ __forceinline__ float siluf_(float x) { return x * sigmoidf_(x); }
__device__ __forceinline__ void split2(float v, bf16& hi, bf16& lo) {
    hi = __float2bfloat16(v);
    lo = __float2bfloat16(v - __bfloat162float(hi));
}

// ---------------------------------------------------------------------------
// MFMA GEMM, 64x64 tile, template BK (64 or 128), 4 waves (each 32x32),
// register prefetch of the next K-tile (BK=128 -> 8x16B in flight/thread).
// C = act(A3 @ W3^T (+bias)) then optional gate-multiply or residual add.
// ACT: 0 none, 1 silu, 2 sigmoid, 3 bias+softplus
// OUTMODE: 0 -> f32 C (ldc=N), 1 -> bf16x3 [hi|lo|hi] rows (stride 3N)
// DT_MODE: stacked dtproj (M=3584=2048+1024+512), per-block W/bias by scale
// GATE: v = res[gm,gn] * v * silu(gxz[gm*2048 + 1024 + gn])   (cg2 fusion)
// ---------------------------------------------------------------------------
template <int BK, int ACT, int OUTMODE, bool ADD_RES, bool DT_MODE, bool GATE>
__global__ __launch_bounds__(256) void mgemm_kernel(
    const bf16* __restrict__ A3, int K3,
    const bf16* __restrict__ W3,
    const float* __restrict__ bias,
    const float* __restrict__ res,     // residual (ADD_RES) or fusedf (GATE)
    const float* __restrict__ gxz,     // xz (GATE)
    float* __restrict__ Cf,
    bf16* __restrict__ Cb3,
    int N)
{
    const int CH = BK / 8;          // 16B chunks per row
    const int RPR = 256 / CH;       // rows staged per round
    const int ROUNDS = 64 / RPR;
    __shared__ bf16 As[64][BK];
    __shared__ bf16 Bs[64][BK];

    const int m0 = blockIdx.x * 64;
    const int n0 = blockIdx.y * 64;
    const int tid = threadIdx.x;
    const int wave = tid >> 6;
    const int lane = tid & 63;
    const int wm = (wave >> 1) * 32;
    const int wn = (wave & 1) * 32;
    const int m16 = lane & 15;
    const int q   = lane >> 4;

    int scale = 0;
    if (DT_MODE) scale = (m0 < 2048) ? 0 : ((m0 < 3072) ? 1 : 2);
    const bf16* Wp = DT_MODE ? (W3 + (size_t)scale * 1024 * K3) : W3;
    const float* bias_p = (ACT == 3) ? (DT_MODE ? bias + scale * N : bias) : nullptr;

    f4v acc[2][2];
#pragma unroll
    for (int i = 0; i < 2; i++)
#pragma unroll
        for (int j = 0; j < 2; j++)
#pragma unroll
            for (int r = 0; r < 4; r++) acc[i][j][r] = 0.f;

    const int cch = tid & (CH - 1);
    const int c8  = cch * 8;
    const int r0  = tid / CH;

    const bf16* Abase = A3 + (size_t)(m0 + r0) * K3 + c8;
    const bf16* Bbase = Wp + (size_t)(n0 + r0) * K3 + c8;
    const size_t rstep = (size_t)RPR * K3;

    const int nkt = K3 / BK;
    uint4 ra[ROUNDS], rb[ROUNDS];
#pragma unroll
    for (int p = 0; p < ROUNDS; p++) {
        ra[p] = *reinterpret_cast<const uint4*>(Abase + p * rstep);
        rb[p] = *reinterpret_cast<const uint4*>(Bbase + p * rstep);
    }

    for (int kt = 0; kt < nkt; kt++) {
        if (kt) __syncthreads();
#pragma unroll
        for (int p = 0; p < ROUNDS; p++) {     // compiler waits vmcnt here
            int r = r0 + p * RPR;
            int sc = (cch ^ (r & 7)) * 8;      // XOR swizzle on 16B chunks
            *reinterpret_cast<uint4*>(&As[r][sc]) = ra[p];
            *reinterpret_cast<uint4*>(&Bs[r][sc]) = rb[p];
        }
        __syncthreads();
        if (kt + 1 < nkt) {                    // prefetch next tile (no wait)
            size_t off = (size_t)(kt + 1) * BK;
#pragma unroll
            for (int p = 0; p < ROUNDS; p++) {
                ra[p] = *reinterpret_cast<const uint4*>(Abase + off + p * rstep);
                rb[p] = *reinterpret_cast<const uint4*>(Bbase + off + p * rstep);
            }
        }
#pragma unroll
        for (int kk = 0; kk < BK / 32; kk++) {
            const int clog = kk * 4 + q;
            s8v af[2], bfr[2];
#pragma unroll
            for (int i = 0; i < 2; i++) {
                int ar = wm + i * 16 + m16;
                af[i]  = *reinterpret_cast<const s8v*>(&As[ar][(clog ^ (ar & 7)) * 8]);
                int br = wn + i * 16 + m16;
                bfr[i] = *reinterpret_cast<const s8v*>(&Bs[br][(clog ^ (br & 7)) * 8]);
            }
#pragma unroll
            for (int i = 0; i < 2; i++)
#pragma unroll
                for (int j = 0; j < 2; j++)
                    acc[i][j] = __builtin_amdgcn_mfma_f32_16x16x32_bf16(
                        af[i], bfr[j], acc[i][j], 0, 0, 0);
        }
    }

    // Epilogue. D mapping (verified): row = q*4 + reg, col = lane&15.
#pragma unroll
    for (int i = 0; i < 2; i++) {
#pragma unroll
        for (int j = 0; j < 2; j++) {
#pragma unroll
            for (int r = 0; r < 4; r++) {
                int gm = m0 + wm + i * 16 + q * 4 + r;
                int gn = n0 + wn + j * 16 + m16;
                float v = acc[i][j][r];
                if (ACT == 3) { v += bias_p[gn]; v = (v > 20.f) ? v : __logf(1.f + __expf(v)); }
                else if (ACT == 1) v = siluf_(v);
                else if (ACT == 2) v = sigmoidf_(v);
                if (GATE)
                    v = res[(size_t)gm * N + gn] * v * siluf_(gxz[(size_t)gm * 2048 + 1024 + gn]);
                else if (ADD_RES)
                    v += res[(size_t)gm * N + gn];
                if (OUTMODE == 0) {
                    Cf[(size_t)gm * N + gn] = v;
                } else {
                    bf16 hi, lo; split2(v, hi, lo);
                    size_t rb_ = (size_t)gm * 3 * N;
                    Cb3[rb_ + gn] = hi;
                    Cb3[rb_ + N + gn] = lo;
                    Cb3[rb_ + 2 * N + gn] = hi;
                }
            }
        }
    }
}

// ---------------------------------------------------------------------------
// One conversion kernel: all weights [Wh|Wh|Wl] + x [hi|lo|hi]
// weights span idx [0, 2818048), x spans [2818048, 3866624)
// ---------------------------------------------------------------------------
__global__ void convert_all_kernel(
    const float* __restrict__ w_in, const float* __restrict__ w_cg1,
    const float* __restrict__ w_cg2, const float* __restrict__ w_out,
    const float* __restrict__ w_dt, const float* __restrict__ x,
    bf16* __restrict__ o_in, bf16* __restrict__ o_cg1, bf16* __restrict__ o_cg2,
    bf16* __restrict__ o_out, bf16* __restrict__ o_dt, bf16* __restrict__ x3)
{
    int idx = blockIdx.x * blockDim.x + threadIdx.x;
    if (idx < 2818048) {
        const float* src; bf16* dst; int lk; int rel;
        if (idx < 1048576)      { src = w_in;  dst = o_in;  lk = 9;  rel = idx; }
        else if (idx < 1572864) { src = w_cg1; dst = o_cg1; lk = 10; rel = idx - 1048576; }
        else if (idx < 2097152) { src = w_cg2; dst = o_cg2; lk = 9;  rel = idx - 1572864; }
        else if (idx < 2621440) { src = w_out; dst = o_out; lk = 10; rel = idx - 2097152; }
        else                    { src = w_dt;  dst = o_dt;  lk = 6;  rel = idx - 2621440; }
        int K = 1 << lk;
        int n = rel >> lk, k = rel & (K - 1);
        bf16 hi, lo; split2(src[rel], hi, lo);
        size_t base = (size_t)n * 3 * K;
        dst[base + k] = hi;
        dst[base + K + k] = hi;
        dst[base + 2 * K + k] = lo;
    } else {
        int rel = idx - 2818048;             // 2048*512
        int m = rel >> 9, k = rel & 511;
        bf16 hi, lo; split2(x[rel], hi, lo);
        size_t base = (size_t)m * 1536;
        x3[base + k] = hi;
        x3[base + 512 + k] = lo;
        x3[base + 1024 + k] = hi;
    }
}

// ---------------------------------------------------------------------------
// Fused downsample + depthwise causal conv(K=4) + bias + SiLU, all 3 scales.
// Output stacked xc (3584 rows x 1024). Reads xz (ld 2048, x_in half).
// idx ranges: s0 [0,2097152) s1 [...,3145728) s2 [...,3670016)
// ---------------------------------------------------------------------------
__global__ void conv_fused_kernel(const float* __restrict__ xz,
                                  const float* __restrict__ cw,   // [3][1024*4]
                                  const float* __restrict__ cb,   // [3][1024]
                                  float* __restrict__ xc)         // stacked
{
    int idx = blockIdx.x * blockDim.x + threadIdx.x;
    if (idx >= 3670016) return;
    int s, rel;
    if (idx < 2097152)      { s = 0; rel = idx; }
    else if (idx < 3145728) { s = 1; rel = idx - 2097152; }
    else                    { s = 2; rel = idx - 3145728; }
    int c = rel & 1023;
    int row = rel >> 10;
    int Ts = 1024 >> s;
    int b = row / Ts;
    int t = row - b * Ts;
    const float* base = xz + (size_t)(b * 1024) * 2048 + c;

    float acc = cb[s * 1024 + c];
#pragma unroll
    for (int k = 0; k < 4; k++) {
        int tau = t - 3 + k;
        if (tau < 0) continue;
        float xv;
        if (s == 0) {
            xv = base[(size_t)tau * 2048];
        } else if (s == 1) {
            xv = 0.5f * (base[(size_t)(2 * tau) * 2048] + base[(size_t)(2 * tau + 1) * 2048]);
        } else {
            xv = 0.25f * (base[(size_t)(4 * tau) * 2048] + base[(size_t)(4 * tau + 1) * 2048]
                        + base[(size_t)(4 * tau + 2) * 2048] + base[(size_t)(4 * tau + 3) * 2048]);
        }
        acc = fmaf(cw[(s * 1024 + c) * 4 + k], xv, acc);
    }
    xc[idx] = siluf_(acc);
}

// ---------------------------------------------------------------------------
// xproj (f32 VALU, N=96): stacked M=3584, BM=BN=32, BK=32 -> grid (112,3).
// Also emits dt_raw (cols<64) as bf16x3 into dtA3 (fused convert).
// ---------------------------------------------------------------------------
__global__ __launch_bounds__(256) void xproj_kernel(
    const float* __restrict__ xc, const float* __restrict__ xw,
    float* __restrict__ pj, bf16* __restrict__ dtA3)
{
    const int m0 = blockIdx.x * 32;
    const int n0 = blockIdx.y * 32;
    const int scale = (m0 < 2048) ? 0 : ((m0 < 3072) ? 1 : 2);
    const float* W = xw + scale * 96 * 1024;

    __shared__ __align__(16) float As[32][36];
    __shared__ __align__(16) float Bs[32][36];
    const int tid = threadIdx.x;
    const int arow = tid >> 3, acol = (tid & 7) * 4;
    const int ty = tid >> 4, tx = tid & 15;

    float acc[2][2] = {};
    for (int k0 = 0; k0 < 1024; k0 += 32) {
        {
            float4 v = *reinterpret_cast<const float4*>(xc + (size_t)(m0 + arow) * 1024 + k0 + acol);
            As[acol + 0][arow] = v.x; As[acol + 1][arow] = v.y;
            As[acol + 2][arow] = v.z; As[acol + 3][arow] = v.w;
        }
        {
            float4 v = *reinterpret_cast<const float4*>(W + (size_t)(n0 + arow) * 1024 + k0 + acol);
            Bs[acol + 0][arow] = v.x; Bs[acol + 1][arow] = v.y;
            Bs[acol + 2][arow] = v.z; Bs[acol + 3][arow] = v.w;
        }
        __syncthreads();
#pragma unroll
        for (int k = 0; k < 32; k++) {
            float a0 = As[k][ty * 2], a1 = As[k][ty * 2 + 1];
            float b0 = Bs[k][tx * 2], b1 = Bs[k][tx * 2 + 1];
            acc[0][0] = fmaf(a0, b0, acc[0][0]);
            acc[0][1] = fmaf(a0, b1, acc[0][1]);
            acc[1][0] = fmaf(a1, b0, acc[1][0]);
            acc[1][1] = fmaf(a1, b1, acc[1][1]);
        }
        __syncthreads();
    }
#pragma unroll
    for (int i = 0; i < 2; i++)
#pragma unroll
        for (int j = 0; j < 2; j++) {
            int row = m0 + ty * 2 + i;
            int col = n0 + tx * 2 + j;
            float v = acc[i][j];
            pj[(size_t)row * 96 + col] = v;
            if (col < 64) {
                bf16 hi, lo; split2(v, hi, lo);
                size_t base = (size_t)row * 192;
                dtA3[base + col] = hi;
                dtA3[base + 64 + col] = lo;
                dtA3[base + 128 + col] = hi;
            }
        }
}

// ---------------------------------------------------------------------------
// Chunked selective scan (unchanged, passing since round 3)
// ---------------------------------------------------------------------------
__device__ __forceinline__ void scan_decode(int blk, int& s, int& nchunk, int& Ts,
                                            int& dquad, int& chunk, int& b, size_t& soff)
{
    int local;
    if (blk < 256)      { s = 0; local = blk;       soff = 0; }
    else if (blk < 384) { s = 1; local = blk - 256; soff = 1048576; }
    else                { s = 2; local = blk - 384; soff = 1572864; }
    nchunk = 32 >> s;
    Ts = 1024 >> s;
    dquad = local & 3;
    chunk = (local >> 2) & (nchunk - 1);
    b = local >> (7 - s);
}

__global__ __launch_bounds__(256) void scan_pass1(
    const float* __restrict__ dt0, const float* __restrict__ xc0, const float* __restrict__ pj0,
    const float* __restrict__ dt1, const float* __restrict__ xc1, const float* __restrict__ pj1,
    const float* __restrict__ dt2, const float* __restrict__ xc2, const float* __restrict__ pj2,
    const float* __restrict__ A_log,
    float* __restrict__ prodA_buf, float* __restrict__ h_buf)
{
    int s, nchunk, Ts, dquad, chunk, b; size_t soff;
    scan_decode(blockIdx.x, s, nchunk, Ts, dquad, chunk, b, soff);
    const float* dt = (s == 0) ? dt0 : (s == 1) ? dt1 : dt2;
    const float* xc = (s == 0) ? xc0 : (s == 1) ? xc1 : xc2;
    const float* pj = (s == 0) ? pj0 : (s == 1) ? pj1 : pj2;

    const int d = dquad * 256 + threadIdx.x;
    const size_t rowbase = (size_t)b * Ts;
    const int t0 = chunk * CHUNK;

    float Acoef[16], h[16], p[16];
#pragma unroll
    for (int j = 0; j < 16; j++) {
        Acoef[j] = -__expf(A_log[((size_t)(s * DINNER + d)) * 16 + j]);
        h[j] = 0.f; p[j] = 1.f;
    }

    __shared__ float bcB[CHUNK][16];
    for (int u = threadIdx.x; u < CHUNK * 16; u += 256) {
        int i = u >> 4, jj = u & 15;
        bcB[i][jj] = pj[(rowbase + t0 + i) * 96 + 64 + jj];
    }
    __syncthreads();

    for (int i = 0; i < CHUNK; i++) {
        size_t t = rowbase + t0 + i;
        float dtv = dt[t * DINNER + d];
        float xv  = xc[t * DINNER + d];
#pragma unroll
        for (int j = 0; j < 16; j++) {
            float dA  = fmaxf(__expf(dtv * Acoef[j]), 1e-38f);
            float dbx = fmaxf(dtv * bcB[i][j] * xv, 1e-38f);
            h[j] = fmaf(dA, h[j], dbx);
            p[j] *= dA;
        }
    }

    size_t base = soff + (size_t)((b * nchunk + chunk) * 16) * 1024 + d;
#pragma unroll
    for (int j = 0; j < 16; j++) {
        prodA_buf[base + (size_t)j * 1024] = p[j];
        h_buf[base + (size_t)j * 1024] = h[j];
    }
}

__global__ __launch_bounds__(256) void scan_pass2(
    const float* __restrict__ dt0, const float* __restrict__ xc0,
    const float* __restrict__ pj0, float* __restrict__ y0,
    const float* __restrict__ dt1, const float* __restrict__ xc1,
    const float* __restrict__ pj1, float* __restrict__ y1,
    const float* __restrict__ dt2, const float* __restrict__ xc2,
    const float* __restrict__ pj2, float* __restrict__ y2,
    const float* __restrict__ A_log, const float* __restrict__ D_p,
    const float* __restrict__ prodA_buf, const float* __restrict__ h_buf)
{
    int s, nchunk, Ts, dquad, chunk, b; size_t soff;
    scan_decode(blockIdx.x, s, nchunk, Ts, dquad, chunk, b, soff);
    const float* dt = (s == 0) ? dt0 : (s == 1) ? dt1 : dt2;
    const float* xc = (s == 0) ? xc0 : (s == 1) ? xc1 : xc2;
    const float* pj = (s == 0) ? pj0 : (s == 1) ? pj1 : pj2;
    float* y        = (s == 0) ? y0  : (s == 1) ? y1  : y2;

    const int d = dquad * 256 + threadIdx.x;
    const size_t rowbase = (size_t)b * Ts;
    const int t0 = chunk * CHUNK;

    float Acoef[16], h[16];
#pragma unroll
    for (int j = 0; j < 16; j++) {
        Acoef[j] = -__expf(A_log[((size_t)(s * DINNER + d)) * 16 + j]);
        h[j] = 0.f;
    }
    const float Dp = D_p[s * DINNER + d];

    for (int c = 0; c < chunk; c++) {
        size_t cb = soff + (size_t)((b * nchunk + c) * 16) * 1024 + d;
#pragma unroll
        for (int j = 0; j < 16; j++)
            h[j] = fmaf(prodA_buf[cb + (size_t)j * 1024], h[j], h_buf[cb + (size_t)j * 1024]);
    }

    __shared__ float bc[CHUNK][32];
    for (int u = threadIdx.x; u < CHUNK * 32; u += 256) {
        int i = u >> 5, jj = u & 31;
        bc[i][jj] = pj[(rowbase + t0 + i) * 96 + 64 + jj];
    }
    __syncthreads();

    for (int i = 0; i < CHUNK; i++) {
        size_t t = rowbase + t0 + i;
        float dtv = dt[t * DINNER + d];
        float xv  = xc[t * DINNER + d];
        float accy = 0.f;
#pragma unroll
        for (int j = 0; j < 16; j++) {
            float dA  = fmaxf(__expf(dtv * Acoef[j]), 1e-38f);
            float dbx = fmaxf(dtv * bc[i][j] * xv, 1e-38f);
            h[j] = fmaf(dA, h[j], dbx);
            accy = fmaf(bc[i][16 + j], h[j], accy);
        }
        y[t * DINNER + d] = accy + Dp * xv;
    }
}

// ---------------------------------------------------------------------------
__global__ void fuse_kernel(const float* __restrict__ y0, const float* __restrict__ y1,
                            const float* __restrict__ y2, const float* __restrict__ sw,
                            float* __restrict__ fused, bf16* __restrict__ ctx3)
{
    int idx = blockIdx.x * blockDim.x + threadIdx.x;
    if (idx >= BATCH * SEQ * DINNER) return;
    int d = idx & (DINNER - 1);
    int t = (idx >> 10) & (SEQ - 1);
    int b = idx >> 20;
    float v0 = y0[idx];
    float v1 = y1[((size_t)(b * 512) + (t >> 1)) * DINNER + d];
    float v2 = y2[((size_t)(b * 256) + (t >> 2)) * DINNER + d];
    float s0 = sw[0], s1 = sw[1], s2 = sw[2];
    float mx = fmaxf(s0, fmaxf(s1, s2));
    float e0 = __expf(s0 - mx), e1 = __expf(s1 - mx), e2 = __expf(s2 - mx);
    float inv = 1.f / (e0 + e1 + e2);
    fused[idx] = (e0 * v0 + e1 * v1 + e2 * v2) * inv;
    float ctxv = (v0 + v1 + v2) * (1.f / 3.f);
    bf16 hi, lo; split2(ctxv, hi, lo);
    size_t rb = (size_t)(idx >> 10) * 3072;
    ctx3[rb + d] = hi;
    ctx3[rb + 1024 + d] = lo;
    ctx3[rb + 2048 + d] = hi;
}

__global__ __launch_bounds__(256) void ln_kernel(
    const float* __restrict__ yin, const float* __restrict__ gamma,
    const float* __restrict__ beta, float* __restrict__ out)
{
    int token = blockIdx.x;
    int tid = threadIdx.x;
    const float* row = yin + (size_t)token * DIMSZ;
    float v0 = row[tid], v1 = row[tid + 256];
    __shared__ float s1[256], s2[256];
    s1[tid] = v0 + v1;
    s2[tid] = v0 * v0 + v1 * v1;
    __syncthreads();
    for (int off = 128; off > 0; off >>= 1) {
        if (tid < off) { s1[tid] += s1[tid + off]; s2[tid] += s2[tid + off]; }
        __syncthreads();
    }
    float mu = s1[0] * (1.f / 512.f);
    float var = s2[0] * (1.f / 512.f) - mu * mu;
    float rstd = rsqrtf(var + 1e-5f);
    float* orow = out + (size_t)token * DIMSZ;
    orow[tid]       = (v0 - mu) * rstd * gamma[tid]       + beta[tid];
    orow[tid + 256] = (v1 - mu) * rstd * gamma[tid + 256] + beta[tid + 256];
}

// ---------------------------------------------------------------------------
extern "C" void kernel_launch(void* const* d_in, const int* in_sizes, int n_in,
                              void* d_out, int out_size, void* d_ws, size_t ws_size,
                              hipStream_t stream)
{
    const float* x         = (const float*)d_in[0];
    const float* in_proj_w = (const float*)d_in[1];
    const float* conv_w    = (const float*)d_in[2];
    const float* conv_b    = (const float*)d_in[3];
    const float* xproj_w   = (const float*)d_in[4];
    const float* dtproj_w  = (const float*)d_in[5];
    const float* dtproj_b  = (const float*)d_in[6];
    const float* A_log     = (const float*)d_in[7];
    const float* D_p       = (const float*)d_in[8];
    const float* scale_w   = (const float*)d_in[9];
    const float* cg_w1     = (const float*)d_in[10];
    const float* cg_w2     = (const float*)d_in[11];
    const float* out_pw    = (const float*)d_in[12];
    const float* ln_gamma  = (const float*)d_in[13];
    const float* ln_beta   = (const float*)d_in[14];
    float* out = (float*)d_out;

    float* ws = (float*)d_ws;
    // f32 base layout (element offsets) — kept from round 5 (xs1/xs2 unused)
    float* xz    = ws;                       // 4,194,304
    float* xs1   = xz    + 4194304;          // 1,048,576 (unused)
    float* xs2   = xs1   + 1048576;          //   524,288 (unused)
    float* xc0   = xs2   + 524288;           // 2,097,152  (xc stacked 3584x1024)
    float* xc1   = xc0   + 2097152;          // 1,048,576
    float* xc2   = xc1   + 1048576;          //   524,288
    float* pj0   = xc2   + 524288;           //   196,608  (pj stacked 3584x96)
    float* pj1   = pj0   + 196608;           //    98,304
    float* pj2   = pj1   + 98304;            //    49,152
    float* dt0   = pj2   + 49152;            // 2,097,152  (dt stacked 3584x1024)
    float* dt1   = dt0   + 2097152;          // 1,048,576
    float* dt2   = dt1   + 1048576;          //   524,288
    float* y0    = dt2   + 524288;           // 2,097,152
    float* y1    = y0    + 2097152;          // 1,048,576
    float* y2    = y1    + 1048576;          //   524,288
    float* prodA = y2    + 524288;           // 1,835,008
    float* hbuf  = prodA + 1835008;          // 1,835,008
    float* w_cg1f = hbuf + 1835008;          //   786,432
    float* w_cg2f = w_cg1f + 786432;         //   786,432
    float* w_outf = w_cg2f + 786432;         //   786,432
    float* w_dtf  = w_outf + 786432;         //   294,912
    float* dtAf   = w_dtf  + 294912;         //   344,064
    // total: 23,789,568 floats = 95.2 MB

    // Overlays (lifetime-checked):
    bf16* w_in3  = (bf16*)y0;     // used P1..P2; y0 written at scan (P7)
    bf16* x3     = (bf16*)y1;     // spans y1+y2; dead after in_proj
    bf16* w_cg13 = (bf16*)w_cg1f;
    bf16* w_cg23 = (bf16*)w_cg2f;
    bf16* w_out3 = (bf16*)w_outf;
    bf16* w_dt3  = (bf16*)w_dtf;
    bf16* dtA3   = (bf16*)dtAf;
    bf16* ctx3   = (bf16*)dt0;    // spans dt0+dt1; dt dead after scan
    bf16* h1cg3  = (bf16*)prodA;  // prodA dead after scan
    bf16* fused3 = (bf16*)y0;     // spans y0+y1; y dead after fuse
    float* fusedf = xc0;          // xc dead after scan
    float* outpre = xc1;

    // P1) conversions (one launch)
    convert_all_kernel<<<15104, 256, 0, stream>>>(
        in_proj_w, cg_w1, cg_w2, out_pw, dtproj_w, x,
        w_in3, w_cg13, w_cg23, w_out3, w_dt3, x3);

    // P2) in_proj (M=2048,N=2048,K3=1536), BK=128 — 1024 blocks
    mgemm_kernel<128, 0, 0, false, false, false><<<dim3(32, 32), 256, 0, stream>>>(
        x3, 1536, w_in3, nullptr, nullptr, nullptr, xz, nullptr, 2048);

    // P3) fused downsample+conv+SiLU, all scales — 14336 blocks
    conv_fused_kernel<<<14336, 256, 0, stream>>>(xz, conv_w, conv_b, xc0);

    // P4) xproj stacked (+ dt_raw bf16x3 emit) — 336 blocks
    xproj_kernel<<<dim3(112, 3), 256, 0, stream>>>(xc0, xproj_w, pj0, dtA3);

    // P5) dtproj stacked (M=3584,N=1024,K3=192), BK=64 — 896 blocks
    mgemm_kernel<64, 3, 0, false, true, false><<<dim3(56, 16), 256, 0, stream>>>(
        dtA3, 192, w_dt3, dtproj_b, nullptr, nullptr, dt0, nullptr, 1024);

    // P6/P7) chunked selective scan
    scan_pass1<<<448, 256, 0, stream>>>(dt0, xc0, pj0, dt1, xc1, pj1,
                                        dt2, xc2, pj2, A_log, prodA, hbuf);
    scan_pass2<<<448, 256, 0, stream>>>(dt0, xc0, pj0, y0, dt1, xc1, pj1, y1,
                                        dt2, xc2, pj2, y2, A_log, D_p, prodA, hbuf);

    // P8) fuse -> fusedf (xc0) + ctx3 (dt0/dt1)
    fuse_kernel<<<(BATCH * SEQ * DINNER) / 256, 256, 0, stream>>>(
        y0, y1, y2, scale_w, fusedf, ctx3);

    // P9) cg1: h1 = silu(ctx @ cg_w1^T) -> bf16x3 (N=512,K3=3072) — 256 blocks
    mgemm_kernel<128, 1, 1, false, false, false><<<dim3(32, 8), 256, 0, stream>>>(
        ctx3, 3072, w_cg13, nullptr, nullptr, nullptr, nullptr, h1cg3, 512);

    // P10) cg2 + gate: fused' = fusedf*sigmoid(h1@cg_w2^T)*silu(gate) -> bf16x3
    //      (N=1024,K3=1536) — 512 blocks
    mgemm_kernel<128, 2, 1, false, false, true><<<dim3(32, 16), 256, 0, stream>>>(
        h1cg3, 1536, w_cg23, nullptr, fusedf, xz, nullptr, fused3, 1024);

    // P11) out_proj + residual (N=512,K3=3072) — 256 blocks
    mgemm_kernel<128, 0, 0, true, false, false><<<dim3(32, 8), 256, 0, stream>>>(
        fused3, 3072, w_out3, nullptr, x, nullptr, outpre, nullptr, 512);

    // P12) LayerNorm
    ln_kernel<<<BATCH * SEQ, 256, 0, stream>>>(outpre, ln_gamma, ln_beta, out);
}

// Round 7
// 311.694 us; speedup vs baseline: 2.3729x; 1.7156x over previous
//
#include <hip/hip_runtime.h>
#include <hip/hip_bf16.h>

// HierarchicalMambaBlock: B=2,T=1024,DIM=512 -> D_INNER=1024, DT_RANK=64, D_STATE=16
// All tensors f32. GEMMs on MFMA via ON-THE-FLY split precision:
// stage f32 tiles into LDS as hi/lo bf16; acc += Ah*Bh + Al*Bh + Ah*Bl (~f32 accurate).
#define BATCH   2
#define SEQ     1024
#define DIMSZ   512
#define DINNER  1024
#define DTRANK  64
#define DSTATE  16
#define CHUNK   32

typedef __hip_bfloat16 bf16;
typedef __attribute__((ext_vector_type(8))) short s8v;   // 8 bf16 MFMA frag
typedef __attribute__((ext_vector_type(4))) float f4v;   // 4 f32 acc

__device__ __forceinline__ float sigmoidf_(float x) { return 1.f / (1.f + __expf(-x)); }
__device__ __forceinline__ float siluf_(float x) { return x * sigmoidf_(x); }
__device__ __forceinline__ void split2(float v, bf16& hi, bf16& lo) {
    hi = __float2bfloat16(v);
    lo = __float2bfloat16(v - __bfloat162float(hi));
}
__device__ __forceinline__ void split_store4(const float4 v,
                                             bf16* __restrict__ ph,
                                             bf16* __restrict__ pl) {
    union { bf16 b[4]; uint2 u; } H, L;
    split2(v.x, H.b[0], L.b[0]); split2(v.y, H.b[1], L.b[1]);
    split2(v.z, H.b[2], L.b[2]); split2(v.w, H.b[3], L.b[3]);
    *reinterpret_cast<uint2*>(ph) = H.u;     // 8B aligned (col multiple of 4)
    *reinterpret_cast<uint2*>(pl) = L.u;
}

// ---------------------------------------------------------------------------
// MFMA GEMM, 64x64 tile, BK=64 f32, 4 waves (each 32x32 of 16x16x32 frags),
// register prefetch of next K-tile. A,W are f32; split to hi/lo at LDS stage.
// C = act(A @ W^T (+bias)), then optional gate-multiply or residual add.
// ACT: 0 none, 1 silu, 2 sigmoid, 3 bias+softplus
// DT_MODE: stacked dtproj (M=3584=2048+1024+512): per-block W/bias by scale
// GATE: v = res[gm,gn] * v * silu(gxz[gm*2048 + 1024 + gn])   (cg2 fusion)
// Requires: M,N multiples of 64 (exact grid), K multiple of 64, lda%4==0.
// ---------------------------------------------------------------------------
template <int ACT, bool ADD_RES, bool DT_MODE, bool GATE>
__global__ __launch_bounds__(256) void mgemm_kernel(
    const float* __restrict__ A, int lda, int K,
    const float* __restrict__ W,            // ldw = K
    const float* __restrict__ bias,
    const float* __restrict__ res,          // residual (ADD_RES) or fusedf (GATE)
    const float* __restrict__ gxz,          // xz (GATE)
    float* __restrict__ C, int N)
{
    // row stride 72 bf16 = 144 B: 16B-aligned for ds_read_b128, rotates banks
    // by 4 per row -> frag reads are 2-way aliased (free). 36 KB total.
    __shared__ bf16 Ah[64][72], Al[64][72], Bh[64][72], Bl[64][72];

    const int m0 = blockIdx.x * 64;
    const int n0 = blockIdx.y * 64;
    const int tid = threadIdx.x;
    const int wave = tid >> 6;
    const int lane = tid & 63;
    const int wm = (wave >> 1) * 32;
    const int wn = (wave & 1) * 32;
    const int m16 = lane & 15;
    const int q   = lane >> 4;

    int scale = 0;
    if (DT_MODE) scale = (m0 < 2048) ? 0 : ((m0 < 3072) ? 1 : 2);
    const float* Wp = DT_MODE ? (W + (size_t)scale * 1024 * K) : W;
    const float* bias_p = (ACT == 3) ? (DT_MODE ? bias + (size_t)scale * N : bias) : nullptr;

    f4v acc[2][2];
#pragma unroll
    for (int i = 0; i < 2; i++)
#pragma unroll
        for (int j = 0; j < 2; j++)
#pragma unroll
            for (int r = 0; r < 4; r++) acc[i][j][r] = 0.f;

    const int cch = tid & 15;       // f32x4 chunk within 64-f32 row (16/row)
    const int c4  = cch * 4;
    const int r0  = tid >> 4;       // 0..15 (4 rounds of 16 rows)

    const float* Abase = A + (size_t)(m0 + r0) * lda + c4;
    const float* Bbase = Wp + (size_t)(n0 + r0) * K + c4;

    const int nkt = K >> 6;
    float4 ra[4], rb[4];
#pragma unroll
    for (int p = 0; p < 4; p++) {
        ra[p] = *reinterpret_cast<const float4*>(Abase + (size_t)(p * 16) * lda);
        rb[p] = *reinterpret_cast<const float4*>(Bbase + (size_t)(p * 16) * K);
    }

    for (int kt = 0; kt < nkt; kt++) {
        if (kt) __syncthreads();
#pragma unroll
        for (int p = 0; p < 4; p++) {        // compiler waits vmcnt here
            int r = r0 + p * 16;
            split_store4(ra[p], &Ah[r][c4], &Al[r][c4]);
            split_store4(rb[p], &Bh[r][c4], &Bl[r][c4]);
        }
        __syncthreads();
        if (kt + 1 < nkt) {                  // prefetch next tile (no wait)
            int off = (kt + 1) * 64;
#pragma unroll
            for (int p = 0; p < 4; p++) {
                ra[p] = *reinterpret_cast<const float4*>(Abase + off + (size_t)(p * 16) * lda);
                rb[p] = *reinterpret_cast<const float4*>(Bbase + off + (size_t)(p * 16) * K);
            }
        }
#pragma unroll
        for (int kk = 0; kk < 2; kk++) {
            const int col = kk * 32 + q * 8;
            s8v ah[2], al[2], bh[2], bl[2];
#pragma unroll
            for (int i = 0; i < 2; i++) {
                int ar = wm + i * 16 + m16;
                ah[i] = *reinterpret_cast<const s8v*>(&Ah[ar][col]);
                al[i] = *reinterpret_cast<const s8v*>(&Al[ar][col]);
                int br = wn + i * 16 + m16;
                bh[i] = *reinterpret_cast<const s8v*>(&Bh[br][col]);
                bl[i] = *reinterpret_cast<const s8v*>(&Bl[br][col]);
            }
#pragma unroll
            for (int i = 0; i < 2; i++)
#pragma unroll
                for (int j = 0; j < 2; j++) {
                    acc[i][j] = __builtin_amdgcn_mfma_f32_16x16x32_bf16(ah[i], bh[j], acc[i][j], 0, 0, 0);
                    acc[i][j] = __builtin_amdgcn_mfma_f32_16x16x32_bf16(al[i], bh[j], acc[i][j], 0, 0, 0);
                    acc[i][j] = __builtin_amdgcn_mfma_f32_16x16x32_bf16(ah[i], bl[j], acc[i][j], 0, 0, 0);
                }
        }
    }

    // Epilogue. D mapping (verified): row = q*4 + reg, col = lane&15.
#pragma unroll
    for (int i = 0; i < 2; i++) {
#pragma unroll
        for (int j = 0; j < 2; j++) {
#pragma unroll
            for (int r = 0; r < 4; r++) {
                int gm = m0 + wm + i * 16 + q * 4 + r;
                int gn = n0 + wn + j * 16 + m16;
                float v = acc[i][j][r];
                if (ACT == 3) { v += bias_p[gn]; v = (v > 20.f) ? v : __logf(1.f + __expf(v)); }
                else if (ACT == 1) v = siluf_(v);
                else if (ACT == 2) v = sigmoidf_(v);
                if (GATE)
                    v = res[(size_t)gm * N + gn] * v * siluf_(gxz[(size_t)gm * 2048 + 1024 + gn]);
                else if (ADD_RES)
                    v += res[(size_t)gm * N + gn];
                C[(size_t)gm * N + gn] = v;
            }
        }
    }
}

// ---------------------------------------------------------------------------
// Fused downsample + depthwise causal conv(K=4) + bias + SiLU, all 3 scales.
// Output stacked xc (3584 rows x 1024). Reads xz (ld 2048, x_in half).
// ---------------------------------------------------------------------------
__global__ void conv_fused_kernel(const float* __restrict__ xz,
                                  const float* __restrict__ cw,   // [3][1024*4]
                                  const float* __restrict__ cb,   // [3][1024]
                                  float* __restrict__ xc)         // stacked
{
    int idx = blockIdx.x * blockDim.x + threadIdx.x;
    if (idx >= 3670016) return;
    int s, rel;
    if (idx < 2097152)      { s = 0; rel = idx; }
    else if (idx < 3145728) { s = 1; rel = idx - 2097152; }
    else                    { s = 2; rel = idx - 3145728; }
    int c = rel & 1023;
    int row = rel >> 10;
    int Ts = 1024 >> s;
    int b = row / Ts;
    int t = row - b * Ts;
    const float* base = xz + (size_t)(b * 1024) * 2048 + c;

    float acc = cb[s * 1024 + c];
#pragma unroll
    for (int k = 0; k < 4; k++) {
        int tau = t - 3 + k;
        if (tau < 0) continue;
        float xv;
        if (s == 0) {
            xv = base[(size_t)tau * 2048];
        } else if (s == 1) {
            xv = 0.5f * (base[(size_t)(2 * tau) * 2048] + base[(size_t)(2 * tau + 1) * 2048]);
        } else {
            xv = 0.25f * (base[(size_t)(4 * tau) * 2048] + base[(size_t)(4 * tau + 1) * 2048]
                        + base[(size_t)(4 * tau + 2) * 2048] + base[(size_t)(4 * tau + 3) * 2048]);
        }
        acc = fmaf(cw[(s * 1024 + c) * 4 + k], xv, acc);
    }
    xc[idx] = siluf_(acc);
}

// ---------------------------------------------------------------------------
// xproj (f32 VALU, N=96): stacked M=3584, BM=BN=32, BK=32 -> grid (112,3).
// ---------------------------------------------------------------------------
__global__ __launch_bounds__(256) void xproj_kernel(
    const float* __restrict__ xc, const float* __restrict__ xw,
    float* __restrict__ pj)
{
    const int m0 = blockIdx.x * 32;
    const int n0 = blockIdx.y * 32;
    const int scale = (m0 < 2048) ? 0 : ((m0 < 3072) ? 1 : 2);
    const float* W = xw + scale * 96 * 1024;

    __shared__ __align__(16) float As[32][36];
    __shared__ __align__(16) float Bs[32][36];
    const int tid = threadIdx.x;
    const int arow = tid >> 3, acol = (tid & 7) * 4;
    const int ty = tid >> 4, tx = tid & 15;

    float acc[2][2] = {};
    for (int k0 = 0; k0 < 1024; k0 += 32) {
        {
            float4 v = *reinterpret_cast<const float4*>(xc + (size_t)(m0 + arow) * 1024 + k0 + acol);
            As[acol + 0][arow] = v.x; As[acol + 1][arow] = v.y;
            As[acol + 2][arow] = v.z; As[acol + 3][arow] = v.w;
        }
        {
            float4 v = *reinterpret_cast<const float4*>(W + (size_t)(n0 + arow) * 1024 + k0 + acol);
            Bs[acol + 0][arow] = v.x; Bs[acol + 1][arow] = v.y;
            Bs[acol + 2][arow] = v.z; Bs[acol + 3][arow] = v.w;
        }
        __syncthreads();
#pragma unroll
        for (int k = 0; k < 32; k++) {
            float a0 = As[k][ty * 2], a1 = As[k][ty * 2 + 1];
            float b0 = Bs[k][tx * 2], b1 = Bs[k][tx * 2 + 1];
            acc[0][0] = fmaf(a0, b0, acc[0][0]);
            acc[0][1] = fmaf(a0, b1, acc[0][1]);
            acc[1][0] = fmaf(a1, b0, acc[1][0]);
            acc[1][1] = fmaf(a1, b1, acc[1][1]);
        }
        __syncthreads();
    }
#pragma unroll
    for (int i = 0; i < 2; i++)
#pragma unroll
        for (int j = 0; j < 2; j++)
            pj[(size_t)(m0 + ty * 2 + i) * 96 + (n0 + tx * 2 + j)] = acc[i][j];
}

// ---------------------------------------------------------------------------
// Chunked selective scan (unchanged, passing since round 3)
// ---------------------------------------------------------------------------
__device__ __forceinline__ void scan_decode(int blk, int& s, int& nchunk, int& Ts,
                                            int& dquad, int& chunk, int& b, size_t& soff)
{
    int local;
    if (blk < 256)      { s = 0; local = blk;       soff = 0; }
    else if (blk < 384) { s = 1; local = blk - 256; soff = 1048576; }
    else                { s = 2; local = blk - 384; soff = 1572864; }
    nchunk = 32 >> s;
    Ts = 1024 >> s;
    dquad = local & 3;
    chunk = (local >> 2) & (nchunk - 1);
    b = local >> (7 - s);
}

__global__ __launch_bounds__(256) void scan_pass1(
    const float* __restrict__ dt0, const float* __restrict__ xc0, const float* __restrict__ pj0,
    const float* __restrict__ dt1, const float* __restrict__ xc1, const float* __restrict__ pj1,
    const float* __restrict__ dt2, const float* __restrict__ xc2, const float* __restrict__ pj2,
    const float* __restrict__ A_log,
    float* __restrict__ prodA_buf, float* __restrict__ h_buf)
{
    int s, nchunk, Ts, dquad, chunk, b; size_t soff;
    scan_decode(blockIdx.x, s, nchunk, Ts, dquad, chunk, b, soff);
    const float* dt = (s == 0) ? dt0 : (s == 1) ? dt1 : dt2;
    const float* xc = (s == 0) ? xc0 : (s == 1) ? xc1 : xc2;
    const float* pj = (s == 0) ? pj0 : (s == 1) ? pj1 : pj2;

    const int d = dquad * 256 + threadIdx.x;
    const size_t rowbase = (size_t)b * Ts;
    const int t0 = chunk * CHUNK;

    float Acoef[16], h[16], p[16];
#pragma unroll
    for (int j = 0; j < 16; j++) {
        Acoef[j] = -__expf(A_log[((size_t)(s * DINNER + d)) * 16 + j]);
        h[j] = 0.f; p[j] = 1.f;
    }

    __shared__ float bcB[CHUNK][16];
    for (int u = threadIdx.x; u < CHUNK * 16; u += 256) {
        int i = u >> 4, jj = u & 15;
        bcB[i][jj] = pj[(rowbase + t0 + i) * 96 + 64 + jj];
    }
    __syncthreads();

    for (int i = 0; i < CHUNK; i++) {
        size_t t = rowbase + t0 + i;
        float dtv = dt[t * DINNER + d];
        float xv  = xc[t * DINNER + d];
#pragma unroll
        for (int j = 0; j < 16; j++) {
            float dA  = fmaxf(__expf(dtv * Acoef[j]), 1e-38f);
            float dbx = fmaxf(dtv * bcB[i][j] * xv, 1e-38f);
            h[j] = fmaf(dA, h[j], dbx);
            p[j] *= dA;
        }
    }

    size_t base = soff + (size_t)((b * nchunk + chunk) * 16) * 1024 + d;
#pragma unroll
    for (int j = 0; j < 16; j++) {
        prodA_buf[base + (size_t)j * 1024] = p[j];
        h_buf[base + (size_t)j * 1024] = h[j];
    }
}

__global__ __launch_bounds__(256) void scan_pass2(
    const float* __restrict__ dt0, const float* __restrict__ xc0,
    const float* __restrict__ pj0, float* __restrict__ y0,
    const float* __restrict__ dt1, const float* __restrict__ xc1,
    const float* __restrict__ pj1, float* __restrict__ y1,
    const float* __restrict__ dt2, const float* __restrict__ xc2,
    const float* __restrict__ pj2, float* __restrict__ y2,
    const float* __restrict__ A_log, const float* __restrict__ D_p,
    const float* __restrict__ prodA_buf, const float* __restrict__ h_buf)
{
    int s, nchunk, Ts, dquad, chunk, b; size_t soff;
    scan_decode(blockIdx.x, s, nchunk, Ts, dquad, chunk, b, soff);
    const float* dt = (s == 0) ? dt0 : (s == 1) ? dt1 : dt2;
    const float* xc = (s == 0) ? xc0 : (s == 1) ? xc1 : xc2;
    const float* pj = (s == 0) ? pj0 : (s == 1) ? pj1 : pj2;
    float* y        = (s == 0) ? y0  : (s == 1) ? y1  : y2;

    const int d = dquad * 256 + threadIdx.x;
    const size_t rowbase = (size_t)b * Ts;
    const int t0 = chunk * CHUNK;

    float Acoef[16], h[16];
#pragma unroll
    for (int j = 0; j < 16; j++) {
        Acoef[j] = -__expf(A_log[((size_t)(s * DINNER + d)) * 16 + j]);
        h[j] = 0.f;
    }
    const float Dp = D_p[s * DINNER + d];

    for (int c = 0; c < chunk; c++) {
        size_t cb = soff + (size_t)((b * nchunk + c) * 16) * 1024 + d;
#pragma unroll
        for (int j = 0; j < 16; j++)
            h[j] = fmaf(prodA_buf[cb + (size_t)j * 1024], h[j], h_buf[cb + (size_t)j * 1024]);
    }

    __shared__ float bc[CHUNK][32];
    for (int u = threadIdx.x; u < CHUNK * 32; u += 256) {
        int i = u >> 5, jj = u & 31;
        bc[i][jj] = pj[(rowbase + t0 + i) * 96 + 64 + jj];
    }
    __syncthreads();

    for (int i = 0; i < CHUNK; i++) {
        size_t t = rowbase + t0 + i;
        float dtv = dt[t * DINNER + d];
        float xv  = xc[t * DINNER + d];
        float accy = 0.f;
#pragma unroll
        for (int j = 0; j < 16; j++) {
            float dA  = fmaxf(__expf(dtv * Acoef[j]), 1e-38f);
            float dbx = fmaxf(dtv * bc[i][j] * xv, 1e-38f);
            h[j] = fmaf(dA, h[j], dbx);
            accy = fmaf(bc[i][16 + j], h[j], accy);
        }
        y[t * DINNER + d] = accy + Dp * xv;
    }
}

// ---------------------------------------------------------------------------
// fused (f32) + ctx (f32) — both plain now
__global__ void fuse_kernel(const float* __restrict__ y0, const float* __restrict__ y1,
                            const float* __restrict__ y2, const float* __restrict__ sw,
                            float* __restrict__ fused, float* __restrict__ ctx)
{
    int idx = blockIdx.x * blockDim.x + threadIdx.x;
    if (idx >= BATCH * SEQ * DINNER) return;
    int d = idx & (DINNER - 1);
    int t = (idx >> 10) & (SEQ - 1);
    int b = idx >> 20;
    float v0 = y0[idx];
    float v1 = y1[((size_t)(b * 512) + (t >> 1)) * DINNER + d];
    float v2 = y2[((size_t)(b * 256) + (t >> 2)) * DINNER + d];
    float s0 = sw[0], s1 = sw[1], s2 = sw[2];
    float mx = fmaxf(s0, fmaxf(s1, s2));
    float e0 = __expf(s0 - mx), e1 = __expf(s1 - mx), e2 = __expf(s2 - mx);
    float inv = 1.f / (e0 + e1 + e2);
    fused[idx] = (e0 * v0 + e1 * v1 + e2 * v2) * inv;
    ctx[idx] = (v0 + v1 + v2) * (1.f / 3.f);
}

__global__ __launch_bounds__(256) void ln_kernel(
    const float* __restrict__ yin, const float* __restrict__ gamma,
    const float* __restrict__ beta, float* __restrict__ out)
{
    int token = blockIdx.x;
    int tid = threadIdx.x;
    const float* row = yin + (size_t)token * DIMSZ;
    float v0 = row[tid], v1 = row[tid + 256];
    __shared__ float s1[256], s2[256];
    s1[tid] = v0 + v1;
    s2[tid] = v0 * v0 + v1 * v1;
    __syncthreads();
    for (int off = 128; off > 0; off >>= 1) {
        if (tid < off) { s1[tid] += s1[tid + off]; s2[tid] += s2[tid + off]; }
        __syncthreads();
    }
    float mu = s1[0] * (1.f / 512.f);
    float var = s2[0] * (1.f / 512.f) - mu * mu;
    float rstd = rsqrtf(var + 1e-5f);
    float* orow = out + (size_t)token * DIMSZ;
    orow[tid]       = (v0 - mu) * rstd * gamma[tid]       + beta[tid];
    orow[tid + 256] = (v1 - mu) * rstd * gamma[tid + 256] + beta[tid + 256];
}

// ---------------------------------------------------------------------------
extern "C" void kernel_launch(void* const* d_in, const int* in_sizes, int n_in,
                              void* d_out, int out_size, void* d_ws, size_t ws_size,
                              hipStream_t stream)
{
    const float* x         = (const float*)d_in[0];
    const float* in_proj_w = (const float*)d_in[1];
    const float* conv_w    = (const float*)d_in[2];
    const float* conv_b    = (const float*)d_in[3];
    const float* xproj_w   = (const float*)d_in[4];
    const float* dtproj_w  = (const float*)d_in[5];
    const float* dtproj_b  = (const float*)d_in[6];
    const float* A_log     = (const float*)d_in[7];
    const float* D_p       = (const float*)d_in[8];
    const float* scale_w   = (const float*)d_in[9];
    const float* cg_w1     = (const float*)d_in[10];
    const float* cg_w2     = (const float*)d_in[11];
    const float* out_pw    = (const float*)d_in[12];
    const float* ln_gamma  = (const float*)d_in[13];
    const float* ln_beta   = (const float*)d_in[14];
    float* out = (float*)d_out;

    float* ws = (float*)d_ws;
    // f32 workspace layout (element offsets)
    float* xz    = ws;                       // 4,194,304  (2048 x 2048)
    float* xc0   = xz    + 4194304;          // 2,097,152  (xc stacked 3584x1024)
    float* xc1   = xc0   + 2097152;          // 1,048,576
    float* xc2   = xc1   + 1048576;          //   524,288
    float* pj0   = xc2   + 524288;           //   196,608  (pj stacked 3584x96)
    float* pj1   = pj0   + 196608;           //    98,304
    float* pj2   = pj1   + 98304;            //    49,152
    float* dt0   = pj2   + 49152;            // 2,097,152  (dt stacked 3584x1024)
    float* dt1   = dt0   + 2097152;          // 1,048,576
    float* dt2   = dt1   + 1048576;          //   524,288
    float* y0    = dt2   + 524288;           // 2,097,152
    float* y1    = y0    + 2097152;          // 1,048,576
    float* y2    = y1    + 1048576;          //   524,288
    float* prodA = y2    + 524288;           // 1,835,008
    float* hbuf  = prodA + 1835008;          // 1,835,008
    // total: 20,217,856 floats = 80.9 MB

    // Overlays (lifetime-checked):
    float* fusedf = xc0;   // written P7 (xc dead after scan)
    float* ctxf   = dt0;   // written P7 (dt dead after scan)
    float* h1     = dt1;   // written P8 (2048 x 512)
    float* fusedg = y0;    // written P9 (y dead after fuse)
    float* outpre = xc1;   // written P10

    // P1) in_proj: xz = x @ in_proj_w^T  (M=2048,N=2048,K=512) — 1024 blocks
    mgemm_kernel<0, false, false, false><<<dim3(32, 32), 256, 0, stream>>>(
        x, DIMSZ, DIMSZ, in_proj_w, nullptr, nullptr, nullptr, xz, 2048);

    // P2) fused downsample+conv+SiLU, all scales — 14336 blocks
    conv_fused_kernel<<<14336, 256, 0, stream>>>(xz, conv_w, conv_b, xc0);

    // P3) xproj stacked — 336 blocks
    xproj_kernel<<<dim3(112, 3), 256, 0, stream>>>(xc0, xproj_w, pj0);

    // P4) dtproj stacked (M=3584,N=1024,K=64, A=pj cols 0..63, lda=96) — 896 blocks
    mgemm_kernel<3, false, true, false><<<dim3(56, 16), 256, 0, stream>>>(
        pj0, 96, DTRANK, dtproj_w, dtproj_b, nullptr, nullptr, dt0, 1024);

    // P5/P6) chunked selective scan
    scan_pass1<<<448, 256, 0, stream>>>(dt0, xc0, pj0, dt1, xc1, pj1,
                                        dt2, xc2, pj2, A_log, prodA, hbuf);
    scan_pass2<<<448, 256, 0, stream>>>(dt0, xc0, pj0, y0, dt1, xc1, pj1, y1,
                                        dt2, xc2, pj2, y2, A_log, D_p, prodA, hbuf);

    // P7) fuse -> fusedf (xc0) + ctxf (dt0)
    fuse_kernel<<<(BATCH * SEQ * DINNER) / 256, 256, 0, stream>>>(
        y0, y1, y2, scale_w, fusedf, ctxf);

    // P8) cg1: h1 = silu(ctx @ cg_w1^T)  (N=512,K=1024) — 256 blocks
    mgemm_kernel<1, false, false, false><<<dim3(32, 8), 256, 0, stream>>>(
        ctxf, DINNER, DINNER, cg_w1, nullptr, nullptr, nullptr, h1, 512);

    // P9) cg2 + gate: fusedg = fusedf * sigmoid(h1 @ cg_w2^T) * silu(gate)
    //     (N=1024,K=512) — 512 blocks
    mgemm_kernel<2, false, false, true><<<dim3(32, 16), 256, 0, stream>>>(
        h1, 512, 512, cg_w2, nullptr, fusedf, xz, fusedg, 1024);

    // P10) out_proj + residual: outpre = fusedg @ out_pw^T + x (N=512,K=1024)
    mgemm_kernel<0, true, false, false><<<dim3(32, 8), 256, 0, stream>>>(
        fusedg, DINNER, DINNER, out_pw, nullptr, x, nullptr, outpre, 512);

    // P11) LayerNorm
    ln_kernel<<<BATCH * SEQ, 256, 0, stream>>>(outpre, ln_gamma, ln_beta, out);
}

// Round 8
// 286.282 us; speedup vs baseline: 2.5836x; 1.0888x over previous
//
#include <hip/hip_runtime.h>
#include <hip/hip_bf16.h>

// HierarchicalMambaBlock: B=2,T=1024,DIM=512 -> D_INNER=1024, DT_RANK=64, D_STATE=16
// All tensors f32. GEMMs on MFMA via ON-THE-FLY split precision:
// stage f32 tiles into LDS as hi/lo bf16; acc += Ah*Bh + Al*Bh + Ah*Bl (~f32 accurate).
#define BATCH   2
#define SEQ     1024
#define DIMSZ   512
#define DINNER  1024
#define DTRANK  64
#define DSTATE  16
#define CHUNK   32

typedef __hip_bfloat16 bf16;
typedef __attribute__((ext_vector_type(8))) short s8v;   // 8 bf16 MFMA frag
typedef __attribute__((ext_vector_type(4))) float f4v;   // 4 f32 acc

__device__ __forceinline__ float sigmoidf_(float x) { return 1.f / (1.f + __expf(-x)); }
__device__ __forceinline__ float siluf_(float x) { return x * sigmoidf_(x); }
__device__ __forceinline__ void split2(float v, bf16& hi, bf16& lo) {
    hi = __float2bfloat16(v);
    lo = __float2bfloat16(v - __bfloat162float(hi));
}
__device__ __forceinline__ void split_store4(const float4 v,
                                             bf16* __restrict__ ph,
                                             bf16* __restrict__ pl) {
    union { bf16 b[4]; uint2 u; } H, L;
    split2(v.x, H.b[0], L.b[0]); split2(v.y, H.b[1], L.b[1]);
    split2(v.z, H.b[2], L.b[2]); split2(v.w, H.b[3], L.b[3]);
    *reinterpret_cast<uint2*>(ph) = H.u;     // 8B aligned (col multiple of 4)
    *reinterpret_cast<uint2*>(pl) = L.u;
}

// ---------------------------------------------------------------------------
// MFMA GEMM, 64x64 tile, BK=64 f32, 4 waves (each 32x32 of 16x16x32 frags),
// register prefetch of next K-tile. A,W are f32; split to hi/lo at LDS stage.
// C = act(A @ W^T (+bias)), then optional gate-multiply or residual add.
// ACT: 0 none, 1 silu, 2 sigmoid, 3 bias+softplus
// DT_MODE: stacked dtproj (M=3584=2048+1024+512): per-block W/bias by scale
// GATE: v = res[gm,gn] * v * silu(gxz[gm*2048 + 1024 + gn])   (cg2 fusion)
// Requires: M,N multiples of 64 (exact grid), K multiple of 64, lda%4==0.
// ---------------------------------------------------------------------------
template <int ACT, bool ADD_RES, bool DT_MODE, bool GATE>
__global__ __launch_bounds__(256) void mgemm_kernel(
    const float* __restrict__ A, int lda, int K,
    const float* __restrict__ W,            // ldw = K
    const float* __restrict__ bias,
    const float* __restrict__ res,          // residual (ADD_RES) or fusedf (GATE)
    const float* __restrict__ gxz,          // xz (GATE)
    float* __restrict__ C, int N)
{
    // row stride 72 bf16 = 144 B: 16B-aligned for ds_read_b128, rotates banks
    // by 4 per row -> frag reads are 2-way aliased (free). 36 KB total.
    __shared__ bf16 Ah[64][72], Al[64][72], Bh[64][72], Bl[64][72];

    const int m0 = blockIdx.x * 64;
    const int n0 = blockIdx.y * 64;
    const int tid = threadIdx.x;
    const int wave = tid >> 6;
    const int lane = tid & 63;
    const int wm = (wave >> 1) * 32;
    const int wn = (wave & 1) * 32;
    const int m16 = lane & 15;
    const int q   = lane >> 4;

    int scale = 0;
    if (DT_MODE) scale = (m0 < 2048) ? 0 : ((m0 < 3072) ? 1 : 2);
    const float* Wp = DT_MODE ? (W + (size_t)scale * 1024 * K) : W;
    const float* bias_p = (ACT == 3) ? (DT_MODE ? bias + (size_t)scale * N : bias) : nullptr;

    f4v acc[2][2];
#pragma unroll
    for (int i = 0; i < 2; i++)
#pragma unroll
        for (int j = 0; j < 2; j++)
#pragma unroll
            for (int r = 0; r < 4; r++) acc[i][j][r] = 0.f;

    const int cch = tid & 15;       // f32x4 chunk within 64-f32 row (16/row)
    const int c4  = cch * 4;
    const int r0  = tid >> 4;       // 0..15 (4 rounds of 16 rows)

    const float* Abase = A + (size_t)(m0 + r0) * lda + c4;
    const float* Bbase = Wp + (size_t)(n0 + r0) * K + c4;

    const int nkt = K >> 6;
    float4 ra[4], rb[4];
#pragma unroll
    for (int p = 0; p < 4; p++) {
        ra[p] = *reinterpret_cast<const float4*>(Abase + (size_t)(p * 16) * lda);
        rb[p] = *reinterpret_cast<const float4*>(Bbase + (size_t)(p * 16) * K);
    }

    for (int kt = 0; kt < nkt; kt++) {
        if (kt) __syncthreads();
#pragma unroll
        for (int p = 0; p < 4; p++) {        // compiler waits vmcnt here
            int r = r0 + p * 16;
            split_store4(ra[p], &Ah[r][c4], &Al[r][c4]);
            split_store4(rb[p], &Bh[r][c4], &Bl[r][c4]);
        }
        __syncthreads();
        if (kt + 1 < nkt) {                  // prefetch next tile (no wait)
            int off = (kt + 1) * 64;
#pragma unroll
            for (int p = 0; p < 4; p++) {
                ra[p] = *reinterpret_cast<const float4*>(Abase + off + (size_t)(p * 16) * lda);
                rb[p] = *reinterpret_cast<const float4*>(Bbase + off + (size_t)(p * 16) * K);
            }
        }
#pragma unroll
        for (int kk = 0; kk < 2; kk++) {
            const int col = kk * 32 + q * 8;
            s8v ah[2], al[2], bh[2], bl[2];
#pragma unroll
            for (int i = 0; i < 2; i++) {
                int ar = wm + i * 16 + m16;
                ah[i] = *reinterpret_cast<const s8v*>(&Ah[ar][col]);
                al[i] = *reinterpret_cast<const s8v*>(&Al[ar][col]);
                int br = wn + i * 16 + m16;
                bh[i] = *reinterpret_cast<const s8v*>(&Bh[br][col]);
                bl[i] = *reinterpret_cast<const s8v*>(&Bl[br][col]);
            }
#pragma unroll
            for (int i = 0; i < 2; i++)
#pragma unroll
                for (int j = 0; j < 2; j++) {
                    acc[i][j] = __builtin_amdgcn_mfma_f32_16x16x32_bf16(ah[i], bh[j], acc[i][j], 0, 0, 0);
                    acc[i][j] = __builtin_amdgcn_mfma_f32_16x16x32_bf16(al[i], bh[j], acc[i][j], 0, 0, 0);
                    acc[i][j] = __builtin_amdgcn_mfma_f32_16x16x32_bf16(ah[i], bl[j], acc[i][j], 0, 0, 0);
                }
        }
    }

    // Epilogue. D mapping (verified): row = q*4 + reg, col = lane&15.
#pragma unroll
    for (int i = 0; i < 2; i++) {
#pragma unroll
        for (int j = 0; j < 2; j++) {
#pragma unroll
            for (int r = 0; r < 4; r++) {
                int gm = m0 + wm + i * 16 + q * 4 + r;
                int gn = n0 + wn + j * 16 + m16;
                float v = acc[i][j][r];
                if (ACT == 3) { v += bias_p[gn]; v = (v > 20.f) ? v : __logf(1.f + __expf(v)); }
                else if (ACT == 1) v = siluf_(v);
                else if (ACT == 2) v = sigmoidf_(v);
                if (GATE)
                    v = res[(size_t)gm * N + gn] * v * siluf_(gxz[(size_t)gm * 2048 + 1024 + gn]);
                else if (ADD_RES)
                    v += res[(size_t)gm * N + gn];
                C[(size_t)gm * N + gn] = v;
            }
        }
    }
}

// ---------------------------------------------------------------------------
// xproj MFMA: stacked M=3584, N=96 (clamped), K=1024, ldc=96.
// Same structure as mgemm; B rows >= 96 stage zeros; writes guarded gn < 96.
// Grid (56, 2). Per-block scale select by m0.
// ---------------------------------------------------------------------------
__global__ __launch_bounds__(256) void xproj_mfma_kernel(
    const float* __restrict__ A,            // xc stacked, lda = 1024
    const float* __restrict__ xw,           // [3][96][1024]
    float* __restrict__ pj)                 // stacked, ldc = 96
{
    const int K = 1024;
    __shared__ bf16 Ah[64][72], Al[64][72], Bh[64][72], Bl[64][72];

    const int m0 = blockIdx.x * 64;
    const int n0 = blockIdx.y * 64;
    const int tid = threadIdx.x;
    const int wave = tid >> 6;
    const int lane = tid & 63;
    const int wm = (wave >> 1) * 32;
    const int wn = (wave & 1) * 32;
    const int m16 = lane & 15;
    const int q   = lane >> 4;

    const int scale = (m0 < 2048) ? 0 : ((m0 < 3072) ? 1 : 2);
    const float* Wp = xw + (size_t)scale * 96 * K;

    f4v acc[2][2];
#pragma unroll
    for (int i = 0; i < 2; i++)
#pragma unroll
        for (int j = 0; j < 2; j++)
#pragma unroll
            for (int r = 0; r < 4; r++) acc[i][j][r] = 0.f;

    const int cch = tid & 15;
    const int c4  = cch * 4;
    const int r0  = tid >> 4;

    const float* Abase = A + (size_t)(m0 + r0) * K + c4;
    const float* Bbase = Wp + (size_t)(n0 + r0) * K + c4;
    bool bok[4];
#pragma unroll
    for (int p = 0; p < 4; p++) bok[p] = (n0 + r0 + p * 16) < 96;

    const int nkt = K >> 6;
    float4 ra[4], rb[4];
    const float4 zero4 = make_float4(0.f, 0.f, 0.f, 0.f);
#pragma unroll
    for (int p = 0; p < 4; p++) {
        ra[p] = *reinterpret_cast<const float4*>(Abase + (size_t)(p * 16) * K);
        rb[p] = bok[p] ? *reinterpret_cast<const float4*>(Bbase + (size_t)(p * 16) * K) : zero4;
    }

    for (int kt = 0; kt < nkt; kt++) {
        if (kt) __syncthreads();
#pragma unroll
        for (int p = 0; p < 4; p++) {
            int r = r0 + p * 16;
            split_store4(ra[p], &Ah[r][c4], &Al[r][c4]);
            split_store4(rb[p], &Bh[r][c4], &Bl[r][c4]);
        }
        __syncthreads();
        if (kt + 1 < nkt) {
            int off = (kt + 1) * 64;
#pragma unroll
            for (int p = 0; p < 4; p++) {
                ra[p] = *reinterpret_cast<const float4*>(Abase + off + (size_t)(p * 16) * K);
                rb[p] = bok[p] ? *reinterpret_cast<const float4*>(Bbase + off + (size_t)(p * 16) * K) : zero4;
            }
        }
#pragma unroll
        for (int kk = 0; kk < 2; kk++) {
            const int col = kk * 32 + q * 8;
            s8v ah[2], al[2], bh[2], bl[2];
#pragma unroll
            for (int i = 0; i < 2; i++) {
                int ar = wm + i * 16 + m16;
                ah[i] = *reinterpret_cast<const s8v*>(&Ah[ar][col]);
                al[i] = *reinterpret_cast<const s8v*>(&Al[ar][col]);
                int br = wn + i * 16 + m16;
                bh[i] = *reinterpret_cast<const s8v*>(&Bh[br][col]);
                bl[i] = *reinterpret_cast<const s8v*>(&Bl[br][col]);
            }
#pragma unroll
            for (int i = 0; i < 2; i++)
#pragma unroll
                for (int j = 0; j < 2; j++) {
                    acc[i][j] = __builtin_amdgcn_mfma_f32_16x16x32_bf16(ah[i], bh[j], acc[i][j], 0, 0, 0);
                    acc[i][j] = __builtin_amdgcn_mfma_f32_16x16x32_bf16(al[i], bh[j], acc[i][j], 0, 0, 0);
                    acc[i][j] = __builtin_amdgcn_mfma_f32_16x16x32_bf16(ah[i], bl[j], acc[i][j], 0, 0, 0);
                }
        }
    }

#pragma unroll
    for (int i = 0; i < 2; i++) {
#pragma unroll
        for (int j = 0; j < 2; j++) {
            int gn = n0 + wn + j * 16 + m16;
            if (gn >= 96) continue;
#pragma unroll
            for (int r = 0; r < 4; r++) {
                int gm = m0 + wm + i * 16 + q * 4 + r;
                pj[(size_t)gm * 96 + gn] = acc[i][j][r];
            }
        }
    }
}

// ---------------------------------------------------------------------------
// Fused downsample + depthwise causal conv(K=4) + bias + SiLU, all 3 scales.
// Output stacked xc (3584 rows x 1024). Reads xz (ld 2048, x_in half).
// ---------------------------------------------------------------------------
__global__ void conv_fused_kernel(const float* __restrict__ xz,
                                  const float* __restrict__ cw,   // [3][1024*4]
                                  const float* __restrict__ cb,   // [3][1024]
                                  float* __restrict__ xc)         // stacked
{
    int idx = blockIdx.x * blockDim.x + threadIdx.x;
    if (idx >= 3670016) return;
    int s, rel;
    if (idx < 2097152)      { s = 0; rel = idx; }
    else if (idx < 3145728) { s = 1; rel = idx - 2097152; }
    else                    { s = 2; rel = idx - 3145728; }
    int c = rel & 1023;
    int row = rel >> 10;
    int Ts = 1024 >> s;
    int b = row / Ts;
    int t = row - b * Ts;
    const float* base = xz + (size_t)(b * 1024) * 2048 + c;

    float acc = cb[s * 1024 + c];
#pragma unroll
    for (int k = 0; k < 4; k++) {
        int tau = t - 3 + k;
        if (tau < 0) continue;
        float xv;
        if (s == 0) {
            xv = base[(size_t)tau * 2048];
        } else if (s == 1) {
            xv = 0.5f * (base[(size_t)(2 * tau) * 2048] + base[(size_t)(2 * tau + 1) * 2048]);
        } else {
            xv = 0.25f * (base[(size_t)(4 * tau) * 2048] + base[(size_t)(4 * tau + 1) * 2048]
                        + base[(size_t)(4 * tau + 2) * 2048] + base[(size_t)(4 * tau + 3) * 2048]);
        }
        acc = fmaf(cw[(s * 1024 + c) * 4 + k], xv, acc);
    }
    xc[idx] = siluf_(acc);
}

// ---------------------------------------------------------------------------
// Chunked selective scan (unchanged, passing since round 3)
// ---------------------------------------------------------------------------
__device__ __forceinline__ void scan_decode(int blk, int& s, int& nchunk, int& Ts,
                                            int& dquad, int& chunk, int& b, size_t& soff)
{
    int local;
    if (blk < 256)      { s = 0; local = blk;       soff = 0; }
    else if (blk < 384) { s = 1; local = blk - 256; soff = 1048576; }
    else                { s = 2; local = blk - 384; soff = 1572864; }
    nchunk = 32 >> s;
    Ts = 1024 >> s;
    dquad = local & 3;
    chunk = (local >> 2) & (nchunk - 1);
    b = local >> (7 - s);
}

__global__ __launch_bounds__(256) void scan_pass1(
    const float* __restrict__ dt0, const float* __restrict__ xc0, const float* __restrict__ pj0,
    const float* __restrict__ dt1, const float* __restrict__ xc1, const float* __restrict__ pj1,
    const float* __restrict__ dt2, const float* __restrict__ xc2, const float* __restrict__ pj2,
    const float* __restrict__ A_log,
    float* __restrict__ prodA_buf, float* __restrict__ h_buf)
{
    int s, nchunk, Ts, dquad, chunk, b; size_t soff;
    scan_decode(blockIdx.x, s, nchunk, Ts, dquad, chunk, b, soff);
    const float* dt = (s == 0) ? dt0 : (s == 1) ? dt1 : dt2;
    const float* xc = (s == 0) ? xc0 : (s == 1) ? xc1 : xc2;
    const float* pj = (s == 0) ? pj0 : (s == 1) ? pj1 : pj2;

    const int d = dquad * 256 + threadIdx.x;
    const size_t rowbase = (size_t)b * Ts;
    const int t0 = chunk * CHUNK;

    float Acoef[16], h[16], p[16];
#pragma unroll
    for (int j = 0; j < 16; j++) {
        Acoef[j] = -__expf(A_log[((size_t)(s * DINNER + d)) * 16 + j]);
        h[j] = 0.f; p[j] = 1.f;
    }

    __shared__ float bcB[CHUNK][16];
    for (int u = threadIdx.x; u < CHUNK * 16; u += 256) {
        int i = u >> 4, jj = u & 15;
        bcB[i][jj] = pj[(rowbase + t0 + i) * 96 + 64 + jj];
    }
    __syncthreads();

    for (int i = 0; i < CHUNK; i++) {
        size_t t = rowbase + t0 + i;
        float dtv = dt[t * DINNER + d];
        float xv  = xc[t * DINNER + d];
#pragma unroll
        for (int j = 0; j < 16; j++) {
            float dA  = fmaxf(__expf(dtv * Acoef[j]), 1e-38f);
            float dbx = fmaxf(dtv * bcB[i][j] * xv, 1e-38f);
            h[j] = fmaf(dA, h[j], dbx);
            p[j] *= dA;
        }
    }

    size_t base = soff + (size_t)((b * nchunk + chunk) * 16) * 1024 + d;
#pragma unroll
    for (int j = 0; j < 16; j++) {
        prodA_buf[base + (size_t)j * 1024] = p[j];
        h_buf[base + (size_t)j * 1024] = h[j];
    }
}

__global__ __launch_bounds__(256) void scan_pass2(
    const float* __restrict__ dt0, const float* __restrict__ xc0,
    const float* __restrict__ pj0, float* __restrict__ y0,
    const float* __restrict__ dt1, const float* __restrict__ xc1,
    const float* __restrict__ pj1, float* __restrict__ y1,
    const float* __restrict__ dt2, const float* __restrict__ xc2,
    const float* __restrict__ pj2, float* __restrict__ y2,
    const float* __restrict__ A_log, const float* __restrict__ D_p,
    const float* __restrict__ prodA_buf, const float* __restrict__ h_buf)
{
    int s, nchunk, Ts, dquad, chunk, b; size_t soff;
    scan_decode(blockIdx.x, s, nchunk, Ts, dquad, chunk, b, soff);
    const float* dt = (s == 0) ? dt0 : (s == 1) ? dt1 : dt2;
    const float* xc = (s == 0) ? xc0 : (s == 1) ? xc1 : xc2;
    const float* pj = (s == 0) ? pj0 : (s == 1) ? pj1 : pj2;
    float* y        = (s == 0) ? y0  : (s == 1) ? y1  : y2;

    const int d = dquad * 256 + threadIdx.x;
    const size_t rowbase = (size_t)b * Ts;
    const int t0 = chunk * CHUNK;

    float Acoef[16], h[16];
#pragma unroll
    for (int j = 0; j < 16; j++) {
        Acoef[j] = -__expf(A_log[((size_t)(s * DINNER + d)) * 16 + j]);
        h[j] = 0.f;
    }
    const float Dp = D_p[s * DINNER + d];

    for (int c = 0; c < chunk; c++) {
        size_t cb = soff + (size_t)((b * nchunk + c) * 16) * 1024 + d;
#pragma unroll
        for (int j = 0; j < 16; j++)
            h[j] = fmaf(prodA_buf[cb + (size_t)j * 1024], h[j], h_buf[cb + (size_t)j * 1024]);
    }

    __shared__ float bc[CHUNK][32];
    for (int u = threadIdx.x; u < CHUNK * 32; u += 256) {
        int i = u >> 5, jj = u & 31;
        bc[i][jj] = pj[(rowbase + t0 + i) * 96 + 64 + jj];
    }
    __syncthreads();

    for (int i = 0; i < CHUNK; i++) {
        size_t t = rowbase + t0 + i;
        float dtv = dt[t * DINNER + d];
        float xv  = xc[t * DINNER + d];
        float accy = 0.f;
#pragma unroll
        for (int j = 0; j < 16; j++) {
            float dA  = fmaxf(__expf(dtv * Acoef[j]), 1e-38f);
            float dbx = fmaxf(dtv * bc[i][j] * xv, 1e-38f);
            h[j] = fmaf(dA, h[j], dbx);
            accy = fmaf(bc[i][16 + j], h[j], accy);
        }
        y[t * DINNER + d] = accy + Dp * xv;
    }
}

// ---------------------------------------------------------------------------
__global__ void fuse_kernel(const float* __restrict__ y0, const float* __restrict__ y1,
                            const float* __restrict__ y2, const float* __restrict__ sw,
                            float* __restrict__ fused, float* __restrict__ ctx)
{
    int idx = blockIdx.x * blockDim.x + threadIdx.x;
    if (idx >= BATCH * SEQ * DINNER) return;
    int d = idx & (DINNER - 1);
    int t = (idx >> 10) & (SEQ - 1);
    int b = idx >> 20;
    float v0 = y0[idx];
    float v1 = y1[((size_t)(b * 512) + (t >> 1)) * DINNER + d];
    float v2 = y2[((size_t)(b * 256) + (t >> 2)) * DINNER + d];
    float s0 = sw[0], s1 = sw[1], s2 = sw[2];
    float mx = fmaxf(s0, fmaxf(s1, s2));
    float e0 = __expf(s0 - mx), e1 = __expf(s1 - mx), e2 = __expf(s2 - mx);
    float inv = 1.f / (e0 + e1 + e2);
    fused[idx] = (e0 * v0 + e1 * v1 + e2 * v2) * inv;
    ctx[idx] = (v0 + v1 + v2) * (1.f / 3.f);
}

__global__ __launch_bounds__(256) void ln_kernel(
    const float* __restrict__ yin, const float* __restrict__ gamma,
    const float* __restrict__ beta, float* __restrict__ out)
{
    int token = blockIdx.x;
    int tid = threadIdx.x;
    const float* row = yin + (size_t)token * DIMSZ;
    float v0 = row[tid], v1 = row[tid + 256];
    __shared__ float s1[256], s2[256];
    s1[tid] = v0 + v1;
    s2[tid] = v0 * v0 + v1 * v1;
    __syncthreads();
    for (int off = 128; off > 0; off >>= 1) {
        if (tid < off) { s1[tid] += s1[tid + off]; s2[tid] += s2[tid + off]; }
        __syncthreads();
    }
    float mu = s1[0] * (1.f / 512.f);
    float var = s2[0] * (1.f / 512.f) - mu * mu;
    float rstd = rsqrtf(var + 1e-5f);
    float* orow = out + (size_t)token * DIMSZ;
    orow[tid]       = (v0 - mu) * rstd * gamma[tid]       + beta[tid];
    orow[tid + 256] = (v1 - mu) * rstd * gamma[tid + 256] + beta[tid + 256];
}

// ---------------------------------------------------------------------------
extern "C" void kernel_launch(void* const* d_in, const int* in_sizes, int n_in,
                              void* d_out, int out_size, void* d_ws, size_t ws_size,
                              hipStream_t stream)
{
    const float* x         = (const float*)d_in[0];
    const float* in_proj_w = (const float*)d_in[1];
    const float* conv_w    = (const float*)d_in[2];
    const float* conv_b    = (const float*)d_in[3];
    const float* xproj_w   = (const float*)d_in[4];
    const float* dtproj_w  = (const float*)d_in[5];
    const float* dtproj_b  = (const float*)d_in[6];
    const float* A_log     = (const float*)d_in[7];
    const float* D_p       = (const float*)d_in[8];
    const float* scale_w   = (const float*)d_in[9];
    const float* cg_w1     = (const float*)d_in[10];
    const float* cg_w2     = (const float*)d_in[11];
    const float* out_pw    = (const float*)d_in[12];
    const float* ln_gamma  = (const float*)d_in[13];
    const float* ln_beta   = (const float*)d_in[14];
    float* out = (float*)d_out;

    float* ws = (float*)d_ws;
    // f32 workspace layout (element offsets)
    float* xz    = ws;                       // 4,194,304  (2048 x 2048)
    float* xc0   = xz    + 4194304;          // 2,097,152  (xc stacked 3584x1024)
    float* xc1   = xc0   + 2097152;          // 1,048,576
    float* xc2   = xc1   + 1048576;          //   524,288
    float* pj0   = xc2   + 524288;           //   196,608  (pj stacked 3584x96)
    float* pj1   = pj0   + 196608;           //    98,304
    float* pj2   = pj1   + 98304;            //    49,152
    float* dt0   = pj2   + 49152;            // 2,097,152  (dt stacked 3584x1024)
    float* dt1   = dt0   + 2097152;          // 1,048,576
    float* dt2   = dt1   + 1048576;          //   524,288
    float* y0    = dt2   + 524288;           // 2,097,152
    float* y1    = y0    + 2097152;          // 1,048,576
    float* y2    = y1    + 1048576;          //   524,288
    float* prodA = y2    + 524288;           // 1,835,008
    float* hbuf  = prodA + 1835008;          // 1,835,008
    // total: 20,217,856 floats = 80.9 MB

    // Overlays (lifetime-checked):
    float* fusedf = xc0;   // written P7 (xc dead after scan)
    float* ctxf   = dt0;   // written P7 (dt dead after scan)
    float* h1     = dt1;   // written P8 (2048 x 512)
    float* fusedg = y0;    // written P9 (y dead after fuse)
    float* outpre = xc1;   // written P10

    // P1) in_proj: xz = x @ in_proj_w^T  (M=2048,N=2048,K=512) — 1024 blocks
    mgemm_kernel<0, false, false, false><<<dim3(32, 32), 256, 0, stream>>>(
        x, DIMSZ, DIMSZ, in_proj_w, nullptr, nullptr, nullptr, xz, 2048);

    // P2) fused downsample+conv+SiLU, all scales — 14336 blocks
    conv_fused_kernel<<<14336, 256, 0, stream>>>(xz, conv_w, conv_b, xc0);

    // P3) xproj stacked, MFMA (M=3584,N=96,K=1024) — 112 blocks
    xproj_mfma_kernel<<<dim3(56, 2), 256, 0, stream>>>(xc0, xproj_w, pj0);

    // P4) dtproj stacked (M=3584,N=1024,K=64, A=pj cols 0..63, lda=96) — 896 blocks
    mgemm_kernel<3, false, true, false><<<dim3(56, 16), 256, 0, stream>>>(
        pj0, 96, DTRANK, dtproj_w, dtproj_b, nullptr, nullptr, dt0, 1024);

    // P5/P6) chunked selective scan
    scan_pass1<<<448, 256, 0, stream>>>(dt0, xc0, pj0, dt1, xc1, pj1,
                                        dt2, xc2, pj2, A_log, prodA, hbuf);
    scan_pass2<<<448, 256, 0, stream>>>(dt0, xc0, pj0, y0, dt1, xc1, pj1, y1,
                                        dt2, xc2, pj2, y2, A_log, D_p, prodA, hbuf);

    // P7) fuse -> fusedf (xc0) + ctxf (dt0)
    fuse_kernel<<<(BATCH * SEQ * DINNER) / 256, 256, 0, stream>>>(
        y0, y1, y2, scale_w, fusedf, ctxf);

    // P8) cg1: h1 = silu(ctx @ cg_w1^T)  (N=512,K=1024) — 256 blocks
    mgemm_kernel<1, false, false, false><<<dim3(32, 8), 256, 0, stream>>>(
        ctxf, DINNER, DINNER, cg_w1, nullptr, nullptr, nullptr, h1, 512);

    // P9) cg2 + gate: fusedg = fusedf * sigmoid(h1 @ cg_w2^T) * silu(gate)
    //     (N=1024,K=512) — 512 blocks
    mgemm_kernel<2, false, false, true><<<dim3(32, 16), 256, 0, stream>>>(
        h1, 512, 512, cg_w2, nullptr, fusedf, xz, fusedg, 1024);

    // P10) out_proj + residual: outpre = fusedg @ out_pw^T + x (N=512,K=1024)
    mgemm_kernel<0, true, false, false><<<dim3(32, 8), 256, 0, stream>>>(
        fusedg, DINNER, DINNER, out_pw, nullptr, x, nullptr, outpre, 512);

    // P11) LayerNorm
    ln_kernel<<<BATCH * SEQ, 256, 0, stream>>>(outpre, ln_gamma, ln_beta, out);
}